// Round 13
// baseline (821.385 us; speedup 1.0000x reference)
//
#include <hip/hip_runtime.h>
#include <math.h>

// ---------------------------------------------------------------------------
// SheafDiffusion on MI355X — round 12: fusion pass (22 -> 16 dispatches).
//  - scan3 absorbs cursor init
//  - embed_h + embed_m fused (LDS overlay restage of the h tile)
//  - params + rotate fused into gnn #2 epilogue (m tile already in-block)
//  - update #1 emits ysh for the next layer
//  - update #2 computes the output projection directly (xs never re-written)
// ---------------------------------------------------------------------------

typedef unsigned short bf16_t;

__device__ __forceinline__ float bf2f(bf16_t u) {
    return __uint_as_float(((unsigned int)u) << 16);
}
__device__ __forceinline__ bf16_t f2bf(float f) {
    unsigned int u = __float_as_uint(f);
    unsigned int r = (u + 0x7FFFu + ((u >> 16) & 1u)) >> 16;  // RNE
    return (bf16_t)r;
}

__device__ __forceinline__ float gelu_tanh(float x) {
    float x3 = x * x * x;
    float t = tanhf(0.7978845608028654f * (x + 0.044715f * x3));
    return 0.5f * x * (1.0f + t);
}

// ---- edge dtype detection ------------------------------------------------
__global__ void k_detect(const int* __restrict__ ei, int* __restrict__ flag) {
    if (blockIdx.x == 0 && threadIdx.x == 0) {
        int is64 = 1;
        for (int i = 1; i < 256; i += 2)
            if (ei[i] != 0) { is64 = 0; break; }
        *flag = is64;
    }
}

// ---- CSR build -----------------------------------------------------------
__global__ void k_hist(const int* __restrict__ ei, const int* __restrict__ flag,
                       int* __restrict__ cnt, int e) {
    int i = blockIdx.x * blockDim.x + threadIdx.x;
    if (i >= e) return;
    int d = (*flag) ? ei[2 * (e + i)] : ei[e + i];
    atomicAdd(&cnt[d], 1);
}

__global__ void k_scan1(const int* __restrict__ cnt, int* __restrict__ row_ptr,
                        int* __restrict__ bs, int n) {
    __shared__ int s[256];
    int i = blockIdx.x * 256 + threadIdx.x;
    int v = (i < n) ? cnt[i] : 0;
    s[threadIdx.x] = v;
    __syncthreads();
#pragma unroll
    for (int off = 1; off < 256; off <<= 1) {
        int add = (threadIdx.x >= off) ? s[threadIdx.x - off] : 0;
        __syncthreads();
        s[threadIdx.x] += add;
        __syncthreads();
    }
    if (i < n) row_ptr[i + 1] = s[threadIdx.x];
    if (threadIdx.x == 255) bs[blockIdx.x] = s[255];
}

__global__ void k_scan2(int* __restrict__ bs, int nt) {
    __shared__ int s[1024];
    int t = threadIdx.x;
    s[t] = (t < nt) ? bs[t] : 0;
    __syncthreads();
#pragma unroll
    for (int off = 1; off < 1024; off <<= 1) {
        int add = (t >= off) ? s[t - off] : 0;
        __syncthreads();
        s[t] += add;
        __syncthreads();
    }
    if (t < nt) bs[t] = (t == 0) ? 0 : s[t - 1];
}

// scan fix-up + cursor init (k_copy fused)
__global__ void k_scan3(int* __restrict__ row_ptr, const int* __restrict__ bs,
                        int* __restrict__ cursor, int n) {
    int i = blockIdx.x * 256 + threadIdx.x;
    if (i < n) {
        int v = row_ptr[i + 1] + bs[blockIdx.x];
        row_ptr[i + 1] = v;
        if (i + 1 < n) cursor[i + 1] = v;
    }
    if (i == 0) { row_ptr[0] = 0; cursor[0] = 0; }
}

// XCD-sharded CSR fill
__global__ void k_fill_shard(const int* __restrict__ ei, const int* __restrict__ flag,
                             int* __restrict__ cursor, int* __restrict__ csr_src,
                             int e, int ns) {
    int g = blockIdx.x & 7;
    int lo = g * ns, hi = lo + ns;
    int is64 = *flag;
    int stride = (gridDim.x >> 3) * blockDim.x;
    int i0 = (blockIdx.x >> 3) * blockDim.x + threadIdx.x;
    for (int i = i0; i < e; i += stride) {
        int d = is64 ? ei[2 * (e + i)] : ei[e + i];
        if (d < lo || d >= hi) continue;
        int s = is64 ? ei[2 * i] : ei[i];
        int pos = atomicAdd(&cursor[d], 1);
        csr_src[pos] = s;
    }
}

// ---- fused embedding: h = x@W_in+b ; m = gelu(h@emb1_W+emb1_b) ------------
__global__ __launch_bounds__(256) void k_embed_hm(const float* __restrict__ x,
                          const float* __restrict__ W_in, const float* __restrict__ b_in,
                          const float* __restrict__ W2, const float* __restrict__ b2,
                          float* __restrict__ h, float* __restrict__ m, int n) {
    __shared__ float sW[128 * 32];   // phase1 W; first 2048 reused as W2 in phase2
    __shared__ float sX[128 * 68];   // phase1 x-tile; first 32*68 reused as hT in phase2
    __shared__ float sb1[32];
    __shared__ float sb2[64];
    int tid = threadIdx.x;
    for (int i = tid; i < 128 * 32; i += 256) sW[i] = W_in[i];
    for (int i = tid; i < 32; i += 256) sb1[i] = b_in[i];
    for (int i = tid; i < 64; i += 256) sb2[i] = b2[i];

    int node0 = blockIdx.x * 64;
    {
        int r = tid >> 2;
        int q0 = tid & 3;
        int node_r = node0 + r;
        const float4* xrow = (const float4*)(x + (size_t)node_r * 128);
#pragma unroll
        for (int qq = 0; qq < 8; qq++) {
            int q = qq * 4 + q0;
            float4 v = (node_r < n) ? xrow[q] : make_float4(0.f, 0.f, 0.f, 0.f);
            sX[(q * 4 + 0) * 68 + r] = v.x;
            sX[(q * 4 + 1) * 68 + r] = v.y;
            sX[(q * 4 + 2) * 68 + r] = v.z;
            sX[(q * 4 + 3) * 68 + r] = v.w;
        }
    }
    __syncthreads();

    // phase 1 GEMM: 64n x 32f, K=128
    int tx = tid & 7;
    int ty = tid >> 3;
    float acc[2][4];
#pragma unroll
    for (int i = 0; i < 2; i++)
#pragma unroll
        for (int j = 0; j < 4; j++) acc[i][j] = 0.0f;

#pragma unroll 4
    for (int k = 0; k < 128; k++) {
        float a0 = sX[k * 68 + ty * 2];
        float a1 = sX[k * 68 + ty * 2 + 1];
        float4 wv = *(const float4*)&sW[k * 32 + tx * 4];
#pragma unroll
        for (int j = 0; j < 4; j++) {
            float w = (&wv.x)[j];
            acc[0][j] += a0 * w;
            acc[1][j] += a1 * w;
        }
    }
    __syncthreads();   // all sX/sW reads done -> safe to overlay

    // write h + restage hT into sX base; load W2 into sW base
    float hv[2][4];
#pragma unroll
    for (int i = 0; i < 2; i++) {
        int node = node0 + ty * 2 + i;
#pragma unroll
        for (int j = 0; j < 4; j++) {
            hv[i][j] = acc[i][j] + sb1[tx * 4 + j];
            sX[(tx * 4 + j) * 68 + (ty * 2 + i)] = hv[i][j];  // hT[k=feat][node]
        }
        if (node < n) {
            float4 o = make_float4(hv[i][0], hv[i][1], hv[i][2], hv[i][3]);
            *(float4*)&h[(size_t)node * 32 + tx * 4] = o;
        }
    }
    for (int i = tid; i < 32 * 64; i += 256) sW[i] = W2[i];
    __syncthreads();

    // phase 2 GEMM: 64n x 64f, K=32
    int tx2 = tid & 15;
    int ty2 = tid >> 4;
    float acc2[4][4];
#pragma unroll
    for (int i = 0; i < 4; i++)
#pragma unroll
        for (int j = 0; j < 4; j++) acc2[i][j] = 0.0f;

#pragma unroll 4
    for (int k = 0; k < 32; k++) {
        float4 av = *(const float4*)&sX[k * 68 + ty2 * 4];
        float4 wv = *(const float4*)&sW[k * 64 + tx2 * 4];
        float a_[4] = {av.x, av.y, av.z, av.w};
#pragma unroll
        for (int i = 0; i < 4; i++)
#pragma unroll
            for (int j = 0; j < 4; j++)
                acc2[i][j] += a_[i] * (&wv.x)[j];
    }
#pragma unroll
    for (int i = 0; i < 4; i++) {
        int node = node0 + ty2 * 4 + i;
        if (node >= n) continue;
        float4 o;
        o.x = gelu_tanh(acc2[i][0] + sb2[tx2 * 4]);
        o.y = gelu_tanh(acc2[i][1] + sb2[tx2 * 4 + 1]);
        o.z = gelu_tanh(acc2[i][2] + sb2[tx2 * 4 + 2]);
        o.w = gelu_tanh(acc2[i][3] + sb2[tx2 * 4 + 3]);
        *(float4*)&m[(size_t)node * 64 + tx2 * 4] = o;
    }
}

// agg[node] = sum over in-edges of m[src] (fp32 rows, x4 unroll)
__global__ void k_gather64(const int* __restrict__ row_ptr, const int* __restrict__ csr_src,
                           const float* __restrict__ m, float* __restrict__ agg, int n) {
    int wave = (blockIdx.x * blockDim.x + threadIdx.x) >> 6;
    int f = threadIdx.x & 63;
    if (wave >= n) return;
    int beg = row_ptr[wave], end = row_ptr[wave + 1];
    float acc = 0.0f;
    int p = beg;
    for (; p + 3 < end; p += 4) {
        int s0 = csr_src[p], s1 = csr_src[p + 1], s2 = csr_src[p + 2], s3 = csr_src[p + 3];
        float a = m[(size_t)s0 * 64 + f];
        float b = m[(size_t)s1 * 64 + f];
        float c = m[(size_t)s2 * 64 + f];
        float d = m[(size_t)s3 * 64 + f];
        acc += (a + b) + (c + d);
    }
    for (; p < end; p++) acc += m[(size_t)csr_src[p] * 64 + f];
    agg[(size_t)wave * 64 + f] = acc;
}

// m_out = gelu(m_in @ Ws + agg @ Wn). If w2 != null: fused params+rotate
// epilogue (theta from the in-block m tile; ysh = bf16(rd*R(th)*xs)).
__global__ __launch_bounds__(256) void k_gnn(const float* m_in, const float* __restrict__ agg,
                      const float* __restrict__ Ws, const float* __restrict__ Wn,
                      float* m_out,
                      const float* w2, const float* b2, const int* row_ptr,
                      const float* xs, float4* params, bf16_t* ysh, int n) {
    __shared__ float sWs[64 * 64];
    __shared__ float sWn[64 * 64];
    __shared__ float sA[64 * 68];   // staging; reused as out-tile for the epilogue
    __shared__ float sw2[64];
    int tid = threadIdx.x;
    for (int i = tid; i < 64 * 64; i += 256) { sWs[i] = Ws[i]; sWn[i] = Wn[i]; }
    if (w2 && tid < 64) sw2[tid] = w2[tid];
    int node0 = blockIdx.x * 64;
    int tx = tid & 15;
    int ty = tid >> 4;
    float acc[4][4];
#pragma unroll
    for (int i = 0; i < 4; i++)
#pragma unroll
        for (int j = 0; j < 4; j++) acc[i][j] = 0.0f;

#pragma unroll
    for (int phase = 0; phase < 2; phase++) {
        const float* A = phase ? agg : m_in;
        __syncthreads();
        int r0 = tid >> 6;
        int c = tid & 63;
#pragma unroll
        for (int rr = 0; rr < 16; rr++) {
            int r = rr * 4 + r0;
            int node = node0 + r;
            float v = (node < n) ? A[(size_t)node * 64 + c] : 0.0f;
            sA[c * 68 + r] = v;
        }
        __syncthreads();
        const float* w = phase ? sWn : sWs;
#pragma unroll 4
        for (int k = 0; k < 64; k++) {
            float4 av = *(const float4*)&sA[k * 68 + ty * 4];
            float4 wv = *(const float4*)&w[k * 64 + tx * 4];
            float a_[4] = {av.x, av.y, av.z, av.w};
#pragma unroll
            for (int i = 0; i < 4; i++)
#pragma unroll
                for (int j = 0; j < 4; j++)
                    acc[i][j] += a_[i] * (&wv.x)[j];
        }
    }
    float o[4][4];
#pragma unroll
    for (int i = 0; i < 4; i++) {
        int node = node0 + ty * 4 + i;
#pragma unroll
        for (int j = 0; j < 4; j++) o[i][j] = gelu_tanh(acc[i][j]);
        if (node < n) {
            float4 ov = make_float4(o[i][0], o[i][1], o[i][2], o[i][3]);
            *(float4*)&m_out[(size_t)node * 64 + tx * 4] = ov;
        }
    }
    if (!w2) return;

    // ---- fused params + rotate epilogue ----
    __syncthreads();   // MAC reads of sA done
#pragma unroll
    for (int i = 0; i < 4; i++) {
        int nl = ty * 4 + i;
#pragma unroll
        for (int j = 0; j < 4; j++) sA[nl * 68 + tx * 4 + j] = o[i][j];  // out[node][feat]
    }
    __syncthreads();
    if (tid < 64) {
        int node = node0 + tid;
        if (node < n) {
            float acc2 = b2[0];
#pragma unroll 8
            for (int k = 0; k < 64; k++) acc2 += sA[tid * 68 + k] * sw2[k];
            float theta = tanhf(acc2);
            float ang = 6.283185307179586f * theta;
            float c = cosf(ang), s = sinf(ang);
            float deg = (float)(row_ptr[node + 1] - row_ptr[node]);
            float rd = rsqrtf(deg + 1.0f);
            params[node] = make_float4(c, s, rd, 0.0f);
            // rotate: ysh = bf16(rd * R(theta) * xs[node])
            const float4* xr = (const float4*)(xs + (size_t)node * 32);
            ushort4* yr = (ushort4*)(ysh + (size_t)node * 32);
#pragma unroll
            for (int q = 0; q < 4; q++) {
                float4 x0 = xr[q];       // feats q*4..q*4+3   (d=0)
                float4 x1 = xr[q + 4];   // feats 16+q*4..     (d=1)
                float y0[4], y1[4];
                float x0_[4] = {x0.x, x0.y, x0.z, x0.w};
                float x1_[4] = {x1.x, x1.y, x1.z, x1.w};
#pragma unroll
                for (int t = 0; t < 4; t++) {
                    y0[t] = rd * (c * x0_[t] - s * x1_[t]);
                    y1[t] = rd * (s * x0_[t] + c * x1_[t]);
                }
                yr[q]     = make_ushort4(f2bf(y0[0]), f2bf(y0[1]), f2bf(y0[2]), f2bf(y0[3]));
                yr[q + 4] = make_ushort4(f2bf(y1[0]), f2bf(y1[1]), f2bf(y1[2]), f2bf(y1[3]));
            }
        }
    }
}

// S[node] = sum over in-edges of ysh[src] (bf16 rows = 1 line, 2 edges/wave)
__global__ void k_gather32(const int* __restrict__ row_ptr, const int* __restrict__ csr_src,
                           const bf16_t* __restrict__ ysh, float* __restrict__ S, int n) {
    int wave = (blockIdx.x * blockDim.x + threadIdx.x) >> 6;
    int lane = threadIdx.x & 63;
    int f = lane & 31;
    int half = lane >> 5;
    if (wave >= n) return;
    int beg = row_ptr[wave], end = row_ptr[wave + 1];
    float acc = 0.0f;
    int p = beg + half;
    for (; p + 2 < end; p += 4) {
        int s0 = csr_src[p], s1 = csr_src[p + 2];
        float a = bf2f(ysh[(size_t)s0 * 32 + f]);
        float b = bf2f(ysh[(size_t)s1 * 32 + f]);
        acc += a + b;
    }
    if (p < end) acc += bf2f(ysh[(size_t)csr_src[p] * 32 + f]);
    acc += __shfl_xor(acc, 32, 64);
    if (half == 0) S[(size_t)wave * 32 + f] = acc;
}

// xs = xs - gelu((xs - rd*R(-th)*S) @ Wd); also emits ysh for the next layer.
__global__ void k_update_mid(float* __restrict__ xs, const float* __restrict__ S,
                             const float4* __restrict__ params, const float* __restrict__ Wd,
                             bf16_t* __restrict__ ysh, int n) {
    __shared__ float sW[256];
    for (int i = threadIdx.x; i < 256; i += blockDim.x) sW[i] = Wd[i];
    __syncthreads();
    int node = blockIdx.x * blockDim.x + threadIdx.x;
    if (node >= n) return;
    float4 pd = params[node];
    float cd = pd.x, sd = pd.y, rd = pd.z;
    float* xrow = xs + (size_t)node * 32;
    const float* srow = S + (size_t)node * 32;
    float a0[16], a1[16];
#pragma unroll
    for (int i = 0; i < 4; i++) {
        float4 s0 = ((const float4*)srow)[i];
        float4 s1 = ((const float4*)(srow + 16))[i];
        float s0_[4] = {s0.x, s0.y, s0.z, s0.w};
        float s1_[4] = {s1.x, s1.y, s1.z, s1.w};
#pragma unroll
        for (int t = 0; t < 4; t++) {
            a0[4 * i + t] = rd * (cd * s0_[t] + sd * s1_[t]);
            a1[4 * i + t] = rd * (cd * s1_[t] - sd * s0_[t]);
        }
    }
    float nx0[16], nx1[16];
#pragma unroll
    for (int dd = 0; dd < 2; dd++) {
        const float* av = dd ? a1 : a0;
        float* nx = dd ? nx1 : nx0;
        float xr[16], lx[16];
        const float4* x4 = (const float4*)(xrow + dd * 16);
#pragma unroll
        for (int i = 0; i < 4; i++) {
            float4 v = x4[i];
            xr[4 * i] = v.x; xr[4 * i + 1] = v.y; xr[4 * i + 2] = v.z; xr[4 * i + 3] = v.w;
            lx[4 * i] = v.x - av[4 * i];
            lx[4 * i + 1] = v.y - av[4 * i + 1];
            lx[4 * i + 2] = v.z - av[4 * i + 2];
            lx[4 * i + 3] = v.w - av[4 * i + 3];
        }
#pragma unroll
        for (int j = 0; j < 16; j++) {
            float acc = 0.0f;
#pragma unroll
            for (int k = 0; k < 16; k++) acc += lx[k] * sW[k * 16 + j];
            nx[j] = xr[j] - gelu_tanh(acc);
        }
    }
    float4* xo = (float4*)xrow;
    ushort4* yr = (ushort4*)(ysh + (size_t)node * 32);
#pragma unroll
    for (int q = 0; q < 4; q++) {
        xo[q]     = make_float4(nx0[4 * q], nx0[4 * q + 1], nx0[4 * q + 2], nx0[4 * q + 3]);
        xo[q + 4] = make_float4(nx1[4 * q], nx1[4 * q + 1], nx1[4 * q + 2], nx1[4 * q + 3]);
        float y0[4], y1[4];
#pragma unroll
        for (int t = 0; t < 4; t++) {
            y0[t] = rd * (cd * nx0[4 * q + t] - sd * nx1[4 * q + t]);
            y1[t] = rd * (sd * nx0[4 * q + t] + cd * nx1[4 * q + t]);
        }
        yr[q]     = make_ushort4(f2bf(y0[0]), f2bf(y0[1]), f2bf(y0[2]), f2bf(y0[3]));
        yr[q + 4] = make_ushort4(f2bf(y1[0]), f2bf(y1[1]), f2bf(y1[2]), f2bf(y1[3]));
    }
}

// final layer: update + output projection fused; xs never written back.
__global__ void k_update_out(const float* __restrict__ xs, const float* __restrict__ S,
                             const float4* __restrict__ params, const float* __restrict__ Wd,
                             const float* __restrict__ Wo, const float* __restrict__ bo,
                             float* __restrict__ out, int n) {
    __shared__ float sW[256];
    __shared__ float sWo[320];
    __shared__ float sbo[10];
    for (int i = threadIdx.x; i < 256; i += blockDim.x) sW[i] = Wd[i];
    for (int i = threadIdx.x; i < 320; i += blockDim.x) sWo[i] = Wo[i];
    for (int i = threadIdx.x; i < 10; i += blockDim.x) sbo[i] = bo[i];
    __syncthreads();
    int node = blockIdx.x * blockDim.x + threadIdx.x;
    if (node >= n) return;
    float4 pd = params[node];
    float cd = pd.x, sd = pd.y, rd = pd.z;
    const float* xrow = xs + (size_t)node * 32;
    const float* srow = S + (size_t)node * 32;
    float a0[16], a1[16];
#pragma unroll
    for (int i = 0; i < 4; i++) {
        float4 s0 = ((const float4*)srow)[i];
        float4 s1 = ((const float4*)(srow + 16))[i];
        float s0_[4] = {s0.x, s0.y, s0.z, s0.w};
        float s1_[4] = {s1.x, s1.y, s1.z, s1.w};
#pragma unroll
        for (int t = 0; t < 4; t++) {
            a0[4 * i + t] = rd * (cd * s0_[t] + sd * s1_[t]);
            a1[4 * i + t] = rd * (cd * s1_[t] - sd * s0_[t]);
        }
    }
    float nx[32];
#pragma unroll
    for (int dd = 0; dd < 2; dd++) {
        const float* av = dd ? a1 : a0;
        float xr[16], lx[16];
        const float4* x4 = (const float4*)(xrow + dd * 16);
#pragma unroll
        for (int i = 0; i < 4; i++) {
            float4 v = x4[i];
            xr[4 * i] = v.x; xr[4 * i + 1] = v.y; xr[4 * i + 2] = v.z; xr[4 * i + 3] = v.w;
            lx[4 * i] = v.x - av[4 * i];
            lx[4 * i + 1] = v.y - av[4 * i + 1];
            lx[4 * i + 2] = v.z - av[4 * i + 2];
            lx[4 * i + 3] = v.w - av[4 * i + 3];
        }
#pragma unroll
        for (int j = 0; j < 16; j++) {
            float acc = 0.0f;
#pragma unroll
            for (int k = 0; k < 16; k++) acc += lx[k] * sW[k * 16 + j];
            nx[dd * 16 + j] = xr[j] - gelu_tanh(acc);
        }
    }
    float* orow = out + (size_t)node * 10;
#pragma unroll
    for (int j = 0; j < 10; j++) {
        float acc = sbo[j];
#pragma unroll
        for (int k = 0; k < 32; k++) acc += nx[k] * sWo[k * 10 + j];
        orow[j] = acc;
    }
}

static inline size_t align256(size_t x) { return (x + 255) & ~(size_t)255; }

extern "C" void kernel_launch(void* const* d_in, const int* in_sizes, int n_in,
                              void* d_out, int out_size, void* d_ws, size_t ws_size,
                              hipStream_t stream) {
    const float* x      = (const float*)d_in[0];
    const int*   ei     = (const int*)d_in[1];
    const float* W_in   = (const float*)d_in[2];
    const float* b_in   = (const float*)d_in[3];
    const float* emb1_W = (const float*)d_in[4];
    const float* emb1_b = (const float*)d_in[5];
    const float* Ws1    = (const float*)d_in[6];
    const float* Wn1    = (const float*)d_in[7];
    const float* Ws2    = (const float*)d_in[8];
    const float* Wn2    = (const float*)d_in[9];
    const float* emb2_W = (const float*)d_in[10];
    const float* emb2_b = (const float*)d_in[11];
    const float* W_diff = (const float*)d_in[12];
    const float* W_out  = (const float*)d_in[13];
    const float* b_out  = (const float*)d_in[14];

    int n = in_sizes[0] / 128;  // 100000
    int e = in_sizes[1] / 2;    // 1600000
    int nt = (n + 255) / 256;
    int ns = (n + 7) / 8;

    char* base = (char*)d_ws;
    size_t off = 0;
    int*    csr_src = (int*)(base + off);    off = align256(off + (size_t)e * 4);
    int*    row_ptr = (int*)(base + off);    off = align256(off + (size_t)(n + 1) * 4);
    int*    cursor  = (int*)(base + off);    off = align256(off + (size_t)n * 4);
    int*    cnt     = (int*)(base + off);    off = align256(off + (size_t)n * 4);
    int*    bsums   = (int*)(base + off);    off = align256(off + (size_t)nt * 4);
    int*    flag    = (int*)(base + off);    off = align256(off + 16);
    float*  h       = (float*)(base + off);  off = align256(off + (size_t)n * 32 * 4);
    float*  m       = (float*)(base + off);  off = align256(off + (size_t)n * 64 * 4);
    bf16_t* ysh     = (bf16_t*)(base + off); off = align256(off + (size_t)n * 32 * 2);
    float*  agg     = (float*)(base + off);  off = align256(off + (size_t)n * 64 * 4);
    float4* params  = (float4*)(base + off);

    int nb = (n + 255) / 256;
    int eb = (e + 255) / 256;
    int tb64 = (n + 63) / 64;

    // CSR build
    k_detect<<<1, 64, 0, stream>>>(ei, flag);
    hipMemsetAsync(cnt, 0, (size_t)n * 4, stream);
    k_hist<<<eb, 256, 0, stream>>>(ei, flag, cnt, e);
    k_scan1<<<nt, 256, 0, stream>>>(cnt, row_ptr, bsums, n);
    k_scan2<<<1, 1024, 0, stream>>>(bsums, nt);
    k_scan3<<<nt, 256, 0, stream>>>(row_ptr, bsums, cursor, n);
    k_fill_shard<<<1024, 256, 0, stream>>>(ei, flag, cursor, csr_src, e, ns);

    // fused embeddings
    k_embed_hm<<<tb64, 256, 0, stream>>>(x, W_in, b_in, emb1_W, emb1_b, h, m, n);

    // sheaf learner GNN layers; gnn #2 fuses params + first rotate
    int gb64 = (n * 64 + 255) / 256;
    k_gather64<<<gb64, 256, 0, stream>>>(row_ptr, csr_src, m, agg, n);
    k_gnn<<<tb64, 256, 0, stream>>>(m, agg, Ws1, Wn1, m,
                                    nullptr, nullptr, nullptr, nullptr, nullptr, nullptr, n);
    k_gather64<<<gb64, 256, 0, stream>>>(row_ptr, csr_src, m, agg, n);
    k_gnn<<<tb64, 256, 0, stream>>>(m, agg, Ws2, Wn2, m,
                                    emb2_W, emb2_b, row_ptr, h, params, ysh, n);

    // diffusion: gather -> update(+rotate) -> gather -> update(+out)
    k_gather32<<<gb64, 256, 0, stream>>>(row_ptr, csr_src, ysh, agg, n);
    k_update_mid<<<nb, 256, 0, stream>>>(h, agg, params, W_diff, ysh, n);
    k_gather32<<<gb64, 256, 0, stream>>>(row_ptr, csr_src, ysh, agg, n);
    k_update_out<<<nb, 256, 0, stream>>>(h, agg, params, W_diff + 256,
                                         W_out, b_out, (float*)d_out, n);
}

// Round 14
// 765.063 us; speedup vs baseline: 1.0736x; 1.0736x over previous
//
#include <hip/hip_runtime.h>
#include <math.h>

// ---------------------------------------------------------------------------
// SheafDiffusion on MI355X — round 13: round-12 fusion + fix k_update_mid/
// k_update_out scratch spill (VGPR_Count=64 with ~96 live floats -> 123MB
// spill writes). __launch_bounds__(256,2) -> 128 VGPR budget, no spill.
// ---------------------------------------------------------------------------

typedef unsigned short bf16_t;

__device__ __forceinline__ float bf2f(bf16_t u) {
    return __uint_as_float(((unsigned int)u) << 16);
}
__device__ __forceinline__ bf16_t f2bf(float f) {
    unsigned int u = __float_as_uint(f);
    unsigned int r = (u + 0x7FFFu + ((u >> 16) & 1u)) >> 16;  // RNE
    return (bf16_t)r;
}

__device__ __forceinline__ float gelu_tanh(float x) {
    float x3 = x * x * x;
    float t = tanhf(0.7978845608028654f * (x + 0.044715f * x3));
    return 0.5f * x * (1.0f + t);
}

// ---- edge dtype detection ------------------------------------------------
__global__ void k_detect(const int* __restrict__ ei, int* __restrict__ flag) {
    if (blockIdx.x == 0 && threadIdx.x == 0) {
        int is64 = 1;
        for (int i = 1; i < 256; i += 2)
            if (ei[i] != 0) { is64 = 0; break; }
        *flag = is64;
    }
}

// ---- CSR build -----------------------------------------------------------
__global__ void k_hist(const int* __restrict__ ei, const int* __restrict__ flag,
                       int* __restrict__ cnt, int e) {
    int i = blockIdx.x * blockDim.x + threadIdx.x;
    if (i >= e) return;
    int d = (*flag) ? ei[2 * (e + i)] : ei[e + i];
    atomicAdd(&cnt[d], 1);
}

__global__ void k_scan1(const int* __restrict__ cnt, int* __restrict__ row_ptr,
                        int* __restrict__ bs, int n) {
    __shared__ int s[256];
    int i = blockIdx.x * 256 + threadIdx.x;
    int v = (i < n) ? cnt[i] : 0;
    s[threadIdx.x] = v;
    __syncthreads();
#pragma unroll
    for (int off = 1; off < 256; off <<= 1) {
        int add = (threadIdx.x >= off) ? s[threadIdx.x - off] : 0;
        __syncthreads();
        s[threadIdx.x] += add;
        __syncthreads();
    }
    if (i < n) row_ptr[i + 1] = s[threadIdx.x];
    if (threadIdx.x == 255) bs[blockIdx.x] = s[255];
}

__global__ void k_scan2(int* __restrict__ bs, int nt) {
    __shared__ int s[1024];
    int t = threadIdx.x;
    s[t] = (t < nt) ? bs[t] : 0;
    __syncthreads();
#pragma unroll
    for (int off = 1; off < 1024; off <<= 1) {
        int add = (t >= off) ? s[t - off] : 0;
        __syncthreads();
        s[t] += add;
        __syncthreads();
    }
    if (t < nt) bs[t] = (t == 0) ? 0 : s[t - 1];
}

// scan fix-up + cursor init (k_copy fused)
__global__ void k_scan3(int* __restrict__ row_ptr, const int* __restrict__ bs,
                        int* __restrict__ cursor, int n) {
    int i = blockIdx.x * 256 + threadIdx.x;
    if (i < n) {
        int v = row_ptr[i + 1] + bs[blockIdx.x];
        row_ptr[i + 1] = v;
        if (i + 1 < n) cursor[i + 1] = v;
    }
    if (i == 0) { row_ptr[0] = 0; cursor[0] = 0; }
}

// XCD-sharded CSR fill
__global__ void k_fill_shard(const int* __restrict__ ei, const int* __restrict__ flag,
                             int* __restrict__ cursor, int* __restrict__ csr_src,
                             int e, int ns) {
    int g = blockIdx.x & 7;
    int lo = g * ns, hi = lo + ns;
    int is64 = *flag;
    int stride = (gridDim.x >> 3) * blockDim.x;
    int i0 = (blockIdx.x >> 3) * blockDim.x + threadIdx.x;
    for (int i = i0; i < e; i += stride) {
        int d = is64 ? ei[2 * (e + i)] : ei[e + i];
        if (d < lo || d >= hi) continue;
        int s = is64 ? ei[2 * i] : ei[i];
        int pos = atomicAdd(&cursor[d], 1);
        csr_src[pos] = s;
    }
}

// ---- fused embedding: h = x@W_in+b ; m = gelu(h@emb1_W+emb1_b) ------------
__global__ __launch_bounds__(256) void k_embed_hm(const float* __restrict__ x,
                          const float* __restrict__ W_in, const float* __restrict__ b_in,
                          const float* __restrict__ W2, const float* __restrict__ b2,
                          float* __restrict__ h, float* __restrict__ m, int n) {
    __shared__ float sW[128 * 32];
    __shared__ float sX[128 * 68];
    __shared__ float sb1[32];
    __shared__ float sb2[64];
    int tid = threadIdx.x;
    for (int i = tid; i < 128 * 32; i += 256) sW[i] = W_in[i];
    for (int i = tid; i < 32; i += 256) sb1[i] = b_in[i];
    for (int i = tid; i < 64; i += 256) sb2[i] = b2[i];

    int node0 = blockIdx.x * 64;
    {
        int r = tid >> 2;
        int q0 = tid & 3;
        int node_r = node0 + r;
        const float4* xrow = (const float4*)(x + (size_t)node_r * 128);
#pragma unroll
        for (int qq = 0; qq < 8; qq++) {
            int q = qq * 4 + q0;
            float4 v = (node_r < n) ? xrow[q] : make_float4(0.f, 0.f, 0.f, 0.f);
            sX[(q * 4 + 0) * 68 + r] = v.x;
            sX[(q * 4 + 1) * 68 + r] = v.y;
            sX[(q * 4 + 2) * 68 + r] = v.z;
            sX[(q * 4 + 3) * 68 + r] = v.w;
        }
    }
    __syncthreads();

    int tx = tid & 7;
    int ty = tid >> 3;
    float acc[2][4];
#pragma unroll
    for (int i = 0; i < 2; i++)
#pragma unroll
        for (int j = 0; j < 4; j++) acc[i][j] = 0.0f;

#pragma unroll 4
    for (int k = 0; k < 128; k++) {
        float a0 = sX[k * 68 + ty * 2];
        float a1 = sX[k * 68 + ty * 2 + 1];
        float4 wv = *(const float4*)&sW[k * 32 + tx * 4];
#pragma unroll
        for (int j = 0; j < 4; j++) {
            float w = (&wv.x)[j];
            acc[0][j] += a0 * w;
            acc[1][j] += a1 * w;
        }
    }
    __syncthreads();

    float hv[2][4];
#pragma unroll
    for (int i = 0; i < 2; i++) {
        int node = node0 + ty * 2 + i;
#pragma unroll
        for (int j = 0; j < 4; j++) {
            hv[i][j] = acc[i][j] + sb1[tx * 4 + j];
            sX[(tx * 4 + j) * 68 + (ty * 2 + i)] = hv[i][j];
        }
        if (node < n) {
            float4 o = make_float4(hv[i][0], hv[i][1], hv[i][2], hv[i][3]);
            *(float4*)&h[(size_t)node * 32 + tx * 4] = o;
        }
    }
    for (int i = tid; i < 32 * 64; i += 256) sW[i] = W2[i];
    __syncthreads();

    int tx2 = tid & 15;
    int ty2 = tid >> 4;
    float acc2[4][4];
#pragma unroll
    for (int i = 0; i < 4; i++)
#pragma unroll
        for (int j = 0; j < 4; j++) acc2[i][j] = 0.0f;

#pragma unroll 4
    for (int k = 0; k < 32; k++) {
        float4 av = *(const float4*)&sX[k * 68 + ty2 * 4];
        float4 wv = *(const float4*)&sW[k * 64 + tx2 * 4];
        float a_[4] = {av.x, av.y, av.z, av.w};
#pragma unroll
        for (int i = 0; i < 4; i++)
#pragma unroll
            for (int j = 0; j < 4; j++)
                acc2[i][j] += a_[i] * (&wv.x)[j];
    }
#pragma unroll
    for (int i = 0; i < 4; i++) {
        int node = node0 + ty2 * 4 + i;
        if (node >= n) continue;
        float4 o;
        o.x = gelu_tanh(acc2[i][0] + sb2[tx2 * 4]);
        o.y = gelu_tanh(acc2[i][1] + sb2[tx2 * 4 + 1]);
        o.z = gelu_tanh(acc2[i][2] + sb2[tx2 * 4 + 2]);
        o.w = gelu_tanh(acc2[i][3] + sb2[tx2 * 4 + 3]);
        *(float4*)&m[(size_t)node * 64 + tx2 * 4] = o;
    }
}

// agg[node] = sum over in-edges of m[src] (fp32 rows, x4 unroll)
__global__ void k_gather64(const int* __restrict__ row_ptr, const int* __restrict__ csr_src,
                           const float* __restrict__ m, float* __restrict__ agg, int n) {
    int wave = (blockIdx.x * blockDim.x + threadIdx.x) >> 6;
    int f = threadIdx.x & 63;
    if (wave >= n) return;
    int beg = row_ptr[wave], end = row_ptr[wave + 1];
    float acc = 0.0f;
    int p = beg;
    for (; p + 3 < end; p += 4) {
        int s0 = csr_src[p], s1 = csr_src[p + 1], s2 = csr_src[p + 2], s3 = csr_src[p + 3];
        float a = m[(size_t)s0 * 64 + f];
        float b = m[(size_t)s1 * 64 + f];
        float c = m[(size_t)s2 * 64 + f];
        float d = m[(size_t)s3 * 64 + f];
        acc += (a + b) + (c + d);
    }
    for (; p < end; p++) acc += m[(size_t)csr_src[p] * 64 + f];
    agg[(size_t)wave * 64 + f] = acc;
}

// m_out = gelu(m_in @ Ws + agg @ Wn). If w2 != null: fused params+rotate.
__global__ __launch_bounds__(256) void k_gnn(const float* m_in, const float* __restrict__ agg,
                      const float* __restrict__ Ws, const float* __restrict__ Wn,
                      float* m_out,
                      const float* w2, const float* b2, const int* row_ptr,
                      const float* xs, float4* params, bf16_t* ysh, int n) {
    __shared__ float sWs[64 * 64];
    __shared__ float sWn[64 * 64];
    __shared__ float sA[64 * 68];
    __shared__ float sw2[64];
    int tid = threadIdx.x;
    for (int i = tid; i < 64 * 64; i += 256) { sWs[i] = Ws[i]; sWn[i] = Wn[i]; }
    if (w2 && tid < 64) sw2[tid] = w2[tid];
    int node0 = blockIdx.x * 64;
    int tx = tid & 15;
    int ty = tid >> 4;
    float acc[4][4];
#pragma unroll
    for (int i = 0; i < 4; i++)
#pragma unroll
        for (int j = 0; j < 4; j++) acc[i][j] = 0.0f;

#pragma unroll
    for (int phase = 0; phase < 2; phase++) {
        const float* A = phase ? agg : m_in;
        __syncthreads();
        int r0 = tid >> 6;
        int c = tid & 63;
#pragma unroll
        for (int rr = 0; rr < 16; rr++) {
            int r = rr * 4 + r0;
            int node = node0 + r;
            float v = (node < n) ? A[(size_t)node * 64 + c] : 0.0f;
            sA[c * 68 + r] = v;
        }
        __syncthreads();
        const float* w = phase ? sWn : sWs;
#pragma unroll 4
        for (int k = 0; k < 64; k++) {
            float4 av = *(const float4*)&sA[k * 68 + ty * 4];
            float4 wv = *(const float4*)&w[k * 64 + tx * 4];
            float a_[4] = {av.x, av.y, av.z, av.w};
#pragma unroll
            for (int i = 0; i < 4; i++)
#pragma unroll
                for (int j = 0; j < 4; j++)
                    acc[i][j] += a_[i] * (&wv.x)[j];
        }
    }
    float o[4][4];
#pragma unroll
    for (int i = 0; i < 4; i++) {
        int node = node0 + ty * 4 + i;
#pragma unroll
        for (int j = 0; j < 4; j++) o[i][j] = gelu_tanh(acc[i][j]);
        if (node < n) {
            float4 ov = make_float4(o[i][0], o[i][1], o[i][2], o[i][3]);
            *(float4*)&m_out[(size_t)node * 64 + tx * 4] = ov;
        }
    }
    if (!w2) return;

    // ---- fused params + rotate epilogue ----
    __syncthreads();
#pragma unroll
    for (int i = 0; i < 4; i++) {
        int nl = ty * 4 + i;
#pragma unroll
        for (int j = 0; j < 4; j++) sA[nl * 68 + tx * 4 + j] = o[i][j];
    }
    __syncthreads();
    if (tid < 64) {
        int node = node0 + tid;
        if (node < n) {
            float acc2 = b2[0];
#pragma unroll 8
            for (int k = 0; k < 64; k++) acc2 += sA[tid * 68 + k] * sw2[k];
            float theta = tanhf(acc2);
            float ang = 6.283185307179586f * theta;
            float c = cosf(ang), s = sinf(ang);
            float deg = (float)(row_ptr[node + 1] - row_ptr[node]);
            float rd = rsqrtf(deg + 1.0f);
            params[node] = make_float4(c, s, rd, 0.0f);
            const float4* xr = (const float4*)(xs + (size_t)node * 32);
            ushort4* yr = (ushort4*)(ysh + (size_t)node * 32);
#pragma unroll
            for (int q = 0; q < 4; q++) {
                float4 x0 = xr[q];
                float4 x1 = xr[q + 4];
                float y0[4], y1[4];
                float x0_[4] = {x0.x, x0.y, x0.z, x0.w};
                float x1_[4] = {x1.x, x1.y, x1.z, x1.w};
#pragma unroll
                for (int t = 0; t < 4; t++) {
                    y0[t] = rd * (c * x0_[t] - s * x1_[t]);
                    y1[t] = rd * (s * x0_[t] + c * x1_[t]);
                }
                yr[q]     = make_ushort4(f2bf(y0[0]), f2bf(y0[1]), f2bf(y0[2]), f2bf(y0[3]));
                yr[q + 4] = make_ushort4(f2bf(y1[0]), f2bf(y1[1]), f2bf(y1[2]), f2bf(y1[3]));
            }
        }
    }
}

// S[node] = sum over in-edges of ysh[src] (bf16 rows = 1 line, 2 edges/wave)
__global__ void k_gather32(const int* __restrict__ row_ptr, const int* __restrict__ csr_src,
                           const bf16_t* __restrict__ ysh, float* __restrict__ S, int n) {
    int wave = (blockIdx.x * blockDim.x + threadIdx.x) >> 6;
    int lane = threadIdx.x & 63;
    int f = lane & 31;
    int half = lane >> 5;
    if (wave >= n) return;
    int beg = row_ptr[wave], end = row_ptr[wave + 1];
    float acc = 0.0f;
    int p = beg + half;
    for (; p + 2 < end; p += 4) {
        int s0 = csr_src[p], s1 = csr_src[p + 2];
        float a = bf2f(ysh[(size_t)s0 * 32 + f]);
        float b = bf2f(ysh[(size_t)s1 * 32 + f]);
        acc += a + b;
    }
    if (p < end) acc += bf2f(ysh[(size_t)csr_src[p] * 32 + f]);
    acc += __shfl_xor(acc, 32, 64);
    if (half == 0) S[(size_t)wave * 32 + f] = acc;
}

// xs = xs - gelu((xs - rd*R(-th)*S) @ Wd); also emits ysh for the next layer.
// __launch_bounds__(256,2): 128 VGPR budget -> no scratch spill (round-12 bug).
__global__ __launch_bounds__(256, 2) void k_update_mid(
                             float* __restrict__ xs, const float* __restrict__ S,
                             const float4* __restrict__ params, const float* __restrict__ Wd,
                             bf16_t* __restrict__ ysh, int n) {
    __shared__ float sW[256];
    for (int i = threadIdx.x; i < 256; i += blockDim.x) sW[i] = Wd[i];
    __syncthreads();
    int node = blockIdx.x * blockDim.x + threadIdx.x;
    if (node >= n) return;
    float4 pd = params[node];
    float cd = pd.x, sd = pd.y, rd = pd.z;
    float* xrow = xs + (size_t)node * 32;
    const float* srow = S + (size_t)node * 32;
    float a0[16], a1[16];
#pragma unroll
    for (int i = 0; i < 4; i++) {
        float4 s0 = ((const float4*)srow)[i];
        float4 s1 = ((const float4*)(srow + 16))[i];
        float s0_[4] = {s0.x, s0.y, s0.z, s0.w};
        float s1_[4] = {s1.x, s1.y, s1.z, s1.w};
#pragma unroll
        for (int t = 0; t < 4; t++) {
            a0[4 * i + t] = rd * (cd * s0_[t] + sd * s1_[t]);
            a1[4 * i + t] = rd * (cd * s1_[t] - sd * s0_[t]);
        }
    }
    float nx0[16], nx1[16];
#pragma unroll
    for (int dd = 0; dd < 2; dd++) {
        const float* av = dd ? a1 : a0;
        float* nx = dd ? nx1 : nx0;
        float xr[16], lx[16];
        const float4* x4 = (const float4*)(xrow + dd * 16);
#pragma unroll
        for (int i = 0; i < 4; i++) {
            float4 v = x4[i];
            xr[4 * i] = v.x; xr[4 * i + 1] = v.y; xr[4 * i + 2] = v.z; xr[4 * i + 3] = v.w;
            lx[4 * i] = v.x - av[4 * i];
            lx[4 * i + 1] = v.y - av[4 * i + 1];
            lx[4 * i + 2] = v.z - av[4 * i + 2];
            lx[4 * i + 3] = v.w - av[4 * i + 3];
        }
#pragma unroll
        for (int j = 0; j < 16; j++) {
            float acc = 0.0f;
#pragma unroll
            for (int k = 0; k < 16; k++) acc += lx[k] * sW[k * 16 + j];
            nx[j] = xr[j] - gelu_tanh(acc);
        }
    }
    float4* xo = (float4*)xrow;
    ushort4* yr = (ushort4*)(ysh + (size_t)node * 32);
#pragma unroll
    for (int q = 0; q < 4; q++) {
        xo[q]     = make_float4(nx0[4 * q], nx0[4 * q + 1], nx0[4 * q + 2], nx0[4 * q + 3]);
        xo[q + 4] = make_float4(nx1[4 * q], nx1[4 * q + 1], nx1[4 * q + 2], nx1[4 * q + 3]);
        float y0[4], y1[4];
#pragma unroll
        for (int t = 0; t < 4; t++) {
            y0[t] = rd * (cd * nx0[4 * q + t] - sd * nx1[4 * q + t]);
            y1[t] = rd * (sd * nx0[4 * q + t] + cd * nx1[4 * q + t]);
        }
        yr[q]     = make_ushort4(f2bf(y0[0]), f2bf(y0[1]), f2bf(y0[2]), f2bf(y0[3]));
        yr[q + 4] = make_ushort4(f2bf(y1[0]), f2bf(y1[1]), f2bf(y1[2]), f2bf(y1[3]));
    }
}

// final layer: update + output projection fused; xs never written back.
__global__ __launch_bounds__(256, 2) void k_update_out(
                             const float* __restrict__ xs, const float* __restrict__ S,
                             const float4* __restrict__ params, const float* __restrict__ Wd,
                             const float* __restrict__ Wo, const float* __restrict__ bo,
                             float* __restrict__ out, int n) {
    __shared__ float sW[256];
    __shared__ float sWo[320];
    __shared__ float sbo[10];
    for (int i = threadIdx.x; i < 256; i += blockDim.x) sW[i] = Wd[i];
    for (int i = threadIdx.x; i < 320; i += blockDim.x) sWo[i] = Wo[i];
    for (int i = threadIdx.x; i < 10; i += blockDim.x) sbo[i] = bo[i];
    __syncthreads();
    int node = blockIdx.x * blockDim.x + threadIdx.x;
    if (node >= n) return;
    float4 pd = params[node];
    float cd = pd.x, sd = pd.y, rd = pd.z;
    const float* xrow = xs + (size_t)node * 32;
    const float* srow = S + (size_t)node * 32;
    float a0[16], a1[16];
#pragma unroll
    for (int i = 0; i < 4; i++) {
        float4 s0 = ((const float4*)srow)[i];
        float4 s1 = ((const float4*)(srow + 16))[i];
        float s0_[4] = {s0.x, s0.y, s0.z, s0.w};
        float s1_[4] = {s1.x, s1.y, s1.z, s1.w};
#pragma unroll
        for (int t = 0; t < 4; t++) {
            a0[4 * i + t] = rd * (cd * s0_[t] + sd * s1_[t]);
            a1[4 * i + t] = rd * (cd * s1_[t] - sd * s0_[t]);
        }
    }
    float nx[32];
#pragma unroll
    for (int dd = 0; dd < 2; dd++) {
        const float* av = dd ? a1 : a0;
        float xr[16], lx[16];
        const float4* x4 = (const float4*)(xrow + dd * 16);
#pragma unroll
        for (int i = 0; i < 4; i++) {
            float4 v = x4[i];
            xr[4 * i] = v.x; xr[4 * i + 1] = v.y; xr[4 * i + 2] = v.z; xr[4 * i + 3] = v.w;
            lx[4 * i] = v.x - av[4 * i];
            lx[4 * i + 1] = v.y - av[4 * i + 1];
            lx[4 * i + 2] = v.z - av[4 * i + 2];
            lx[4 * i + 3] = v.w - av[4 * i + 3];
        }
#pragma unroll
        for (int j = 0; j < 16; j++) {
            float acc = 0.0f;
#pragma unroll
            for (int k = 0; k < 16; k++) acc += lx[k] * sW[k * 16 + j];
            nx[dd * 16 + j] = xr[j] - gelu_tanh(acc);
        }
    }
    float* orow = out + (size_t)node * 10;
#pragma unroll
    for (int j = 0; j < 10; j++) {
        float acc = sbo[j];
#pragma unroll
        for (int k = 0; k < 32; k++) acc += nx[k] * sWo[k * 10 + j];
        orow[j] = acc;
    }
}

static inline size_t align256(size_t x) { return (x + 255) & ~(size_t)255; }

extern "C" void kernel_launch(void* const* d_in, const int* in_sizes, int n_in,
                              void* d_out, int out_size, void* d_ws, size_t ws_size,
                              hipStream_t stream) {
    const float* x      = (const float*)d_in[0];
    const int*   ei     = (const int*)d_in[1];
    const float* W_in   = (const float*)d_in[2];
    const float* b_in   = (const float*)d_in[3];
    const float* emb1_W = (const float*)d_in[4];
    const float* emb1_b = (const float*)d_in[5];
    const float* Ws1    = (const float*)d_in[6];
    const float* Wn1    = (const float*)d_in[7];
    const float* Ws2    = (const float*)d_in[8];
    const float* Wn2    = (const float*)d_in[9];
    const float* emb2_W = (const float*)d_in[10];
    const float* emb2_b = (const float*)d_in[11];
    const float* W_diff = (const float*)d_in[12];
    const float* W_out  = (const float*)d_in[13];
    const float* b_out  = (const float*)d_in[14];

    int n = in_sizes[0] / 128;  // 100000
    int e = in_sizes[1] / 2;    // 1600000
    int nt = (n + 255) / 256;
    int ns = (n + 7) / 8;

    char* base = (char*)d_ws;
    size_t off = 0;
    int*    csr_src = (int*)(base + off);    off = align256(off + (size_t)e * 4);
    int*    row_ptr = (int*)(base + off);    off = align256(off + (size_t)(n + 1) * 4);
    int*    cursor  = (int*)(base + off);    off = align256(off + (size_t)n * 4);
    int*    cnt     = (int*)(base + off);    off = align256(off + (size_t)n * 4);
    int*    bsums   = (int*)(base + off);    off = align256(off + (size_t)nt * 4);
    int*    flag    = (int*)(base + off);    off = align256(off + 16);
    float*  h       = (float*)(base + off);  off = align256(off + (size_t)n * 32 * 4);
    float*  m       = (float*)(base + off);  off = align256(off + (size_t)n * 64 * 4);
    bf16_t* ysh     = (bf16_t*)(base + off); off = align256(off + (size_t)n * 32 * 2);
    float*  agg     = (float*)(base + off);  off = align256(off + (size_t)n * 64 * 4);
    float4* params  = (float4*)(base + off);

    int nb = (n + 255) / 256;
    int eb = (e + 255) / 256;
    int tb64 = (n + 63) / 64;

    // CSR build
    k_detect<<<1, 64, 0, stream>>>(ei, flag);
    hipMemsetAsync(cnt, 0, (size_t)n * 4, stream);
    k_hist<<<eb, 256, 0, stream>>>(ei, flag, cnt, e);
    k_scan1<<<nt, 256, 0, stream>>>(cnt, row_ptr, bsums, n);
    k_scan2<<<1, 1024, 0, stream>>>(bsums, nt);
    k_scan3<<<nt, 256, 0, stream>>>(row_ptr, bsums, cursor, n);
    k_fill_shard<<<1024, 256, 0, stream>>>(ei, flag, cursor, csr_src, e, ns);

    // fused embeddings
    k_embed_hm<<<tb64, 256, 0, stream>>>(x, W_in, b_in, emb1_W, emb1_b, h, m, n);

    // sheaf learner GNN layers; gnn #2 fuses params + first rotate
    int gb64 = (n * 64 + 255) / 256;
    k_gather64<<<gb64, 256, 0, stream>>>(row_ptr, csr_src, m, agg, n);
    k_gnn<<<tb64, 256, 0, stream>>>(m, agg, Ws1, Wn1, m,
                                    nullptr, nullptr, nullptr, nullptr, nullptr, nullptr, n);
    k_gather64<<<gb64, 256, 0, stream>>>(row_ptr, csr_src, m, agg, n);
    k_gnn<<<tb64, 256, 0, stream>>>(m, agg, Ws2, Wn2, m,
                                    emb2_W, emb2_b, row_ptr, h, params, ysh, n);

    // diffusion: gather -> update(+rotate) -> gather -> update(+out)
    k_gather32<<<gb64, 256, 0, stream>>>(row_ptr, csr_src, ysh, agg, n);
    k_update_mid<<<nb, 256, 0, stream>>>(h, agg, params, W_diff, ysh, n);
    k_gather32<<<gb64, 256, 0, stream>>>(row_ptr, csr_src, ysh, agg, n);
    k_update_out<<<nb, 256, 0, stream>>>(h, agg, params, W_diff + 256,
                                         W_out, b_out, (float*)d_out, n);
}

// Round 15
// 748.110 us; speedup vs baseline: 1.0979x; 1.0227x over previous
//
#include <hip/hip_runtime.h>
#include <math.h>

// ---------------------------------------------------------------------------
// SheafDiffusion on MI355X — round 14: two-phase radix CSR fill with bulk
// reservation. Phase 1: per-block LDS shard-histogram + ONE global atomic per
// (block,shard) + sequential int2 runs (fixes round-8's per-edge cursor
// contention). Phase 2: per-shard LDS-cursor distribute into a ~50KB
// L2-local csr window (fixes round-13 fill's 70MB line thrash).
// ---------------------------------------------------------------------------

typedef unsigned short bf16_t;

#define NSHARD 128
#define CHUNK 4096

__device__ __forceinline__ float bf2f(bf16_t u) {
    return __uint_as_float(((unsigned int)u) << 16);
}
__device__ __forceinline__ bf16_t f2bf(float f) {
    unsigned int u = __float_as_uint(f);
    unsigned int r = (u + 0x7FFFu + ((u >> 16) & 1u)) >> 16;  // RNE
    return (bf16_t)r;
}

__device__ __forceinline__ float gelu_tanh(float x) {
    float x3 = x * x * x;
    float t = tanhf(0.7978845608028654f * (x + 0.044715f * x3));
    return 0.5f * x * (1.0f + t);
}

// ---- edge dtype detection ------------------------------------------------
__global__ void k_detect(const int* __restrict__ ei, int* __restrict__ flag) {
    if (blockIdx.x == 0 && threadIdx.x == 0) {
        int is64 = 1;
        for (int i = 1; i < 256; i += 2)
            if (ei[i] != 0) { is64 = 0; break; }
        *flag = is64;
    }
}

// ---- CSR build -----------------------------------------------------------
__global__ void k_hist(const int* __restrict__ ei, const int* __restrict__ flag,
                       int* __restrict__ cnt, int e) {
    int i = blockIdx.x * blockDim.x + threadIdx.x;
    if (i >= e) return;
    int d = (*flag) ? ei[2 * (e + i)] : ei[e + i];
    atomicAdd(&cnt[d], 1);
}

__global__ void k_scan1(const int* __restrict__ cnt, int* __restrict__ row_ptr,
                        int* __restrict__ bs, int n) {
    __shared__ int s[256];
    int i = blockIdx.x * 256 + threadIdx.x;
    int v = (i < n) ? cnt[i] : 0;
    s[threadIdx.x] = v;
    __syncthreads();
#pragma unroll
    for (int off = 1; off < 256; off <<= 1) {
        int add = (threadIdx.x >= off) ? s[threadIdx.x - off] : 0;
        __syncthreads();
        s[threadIdx.x] += add;
        __syncthreads();
    }
    if (i < n) row_ptr[i + 1] = s[threadIdx.x];
    if (threadIdx.x == 255) bs[blockIdx.x] = s[255];
}

__global__ void k_scan2(int* __restrict__ bs, int nt) {
    __shared__ int s[1024];
    int t = threadIdx.x;
    s[t] = (t < nt) ? bs[t] : 0;
    __syncthreads();
#pragma unroll
    for (int off = 1; off < 1024; off <<= 1) {
        int add = (t >= off) ? s[t - off] : 0;
        __syncthreads();
        s[t] += add;
        __syncthreads();
    }
    if (t < nt) bs[t] = (t == 0) ? 0 : s[t - 1];
}

__global__ void k_scan3(int* __restrict__ row_ptr, const int* __restrict__ bs, int n) {
    int i = blockIdx.x * 256 + threadIdx.x;
    if (i < n) row_ptr[i + 1] += bs[blockIdx.x];
    if (i == 0) row_ptr[0] = 0;
}

// bcur[s] = row_ptr[shard start]
__global__ void k_binit(const int* __restrict__ row_ptr, int* __restrict__ bcur,
                        int sn, int n) {
    int s = threadIdx.x;
    if (s < NSHARD) {
        int node = s * sn;
        if (node > n) node = n;
        bcur[s] = row_ptr[node];
    }
}

// phase 1: partition edges into shard regions of ebuf with bulk reservation
__global__ __launch_bounds__(256) void k_partition(const int* __restrict__ ei,
                        const int* __restrict__ flag, int* __restrict__ bcur,
                        int2* __restrict__ ebuf, int e, int sn) {
    __shared__ int lcnt[NSHARD];
    __shared__ int lbase[NSHARD];
    int is64 = *flag;
    int beg = blockIdx.x * CHUNK;
    int end = min(beg + CHUNK, e);
    if (threadIdx.x < NSHARD) lcnt[threadIdx.x] = 0;
    __syncthreads();
    // pass 1: count
    for (int i = beg + threadIdx.x; i < end; i += 256) {
        int d = is64 ? ei[2 * (e + i)] : ei[e + i];
        atomicAdd(&lcnt[d / sn], 1);
    }
    __syncthreads();
    if (threadIdx.x < NSHARD) {
        int c = lcnt[threadIdx.x];
        lbase[threadIdx.x] = (c > 0) ? atomicAdd(&bcur[threadIdx.x], c) : 0;
        lcnt[threadIdx.x] = 0;
    }
    __syncthreads();
    // pass 2: place
    for (int i = beg + threadIdx.x; i < end; i += 256) {
        int d = is64 ? ei[2 * (e + i)] : ei[e + i];
        int s = is64 ? ei[2 * i] : ei[i];
        int sh = d / sn;
        int pos = lbase[sh] + atomicAdd(&lcnt[sh], 1);
        ebuf[pos] = make_int2(s, d);
    }
}

// phase 2: one block per shard; distribute to per-node csr slots via LDS cursors
__global__ __launch_bounds__(256) void k_distribute(const int* __restrict__ row_ptr,
                        const int2* __restrict__ ebuf, int* __restrict__ csr_src,
                        int sn, int n) {
    __shared__ int lcur[1024];   // sn <= 1024
    int node0 = blockIdx.x * sn;
    if (node0 >= n) return;
    int nloc = min(sn, n - node0);
    for (int j = threadIdx.x; j < nloc; j += 256) lcur[j] = row_ptr[node0 + j];
    __syncthreads();
    int beg = row_ptr[node0];
    int end = row_ptr[node0 + nloc];
    for (int p = beg + threadIdx.x; p < end; p += 256) {
        int2 ed = ebuf[p];
        int pos = atomicAdd(&lcur[ed.y - node0], 1);
        csr_src[pos] = ed.x;
    }
}

// ---- fused embedding: h = x@W_in+b ; m = gelu(h@emb1_W+emb1_b) ------------
__global__ __launch_bounds__(256) void k_embed_hm(const float* __restrict__ x,
                          const float* __restrict__ W_in, const float* __restrict__ b_in,
                          const float* __restrict__ W2, const float* __restrict__ b2,
                          float* __restrict__ h, float* __restrict__ m, int n) {
    __shared__ float sW[128 * 32];
    __shared__ float sX[128 * 68];
    __shared__ float sb1[32];
    __shared__ float sb2[64];
    int tid = threadIdx.x;
    for (int i = tid; i < 128 * 32; i += 256) sW[i] = W_in[i];
    for (int i = tid; i < 32; i += 256) sb1[i] = b_in[i];
    for (int i = tid; i < 64; i += 256) sb2[i] = b2[i];

    int node0 = blockIdx.x * 64;
    {
        int r = tid >> 2;
        int q0 = tid & 3;
        int node_r = node0 + r;
        const float4* xrow = (const float4*)(x + (size_t)node_r * 128);
#pragma unroll
        for (int qq = 0; qq < 8; qq++) {
            int q = qq * 4 + q0;
            float4 v = (node_r < n) ? xrow[q] : make_float4(0.f, 0.f, 0.f, 0.f);
            sX[(q * 4 + 0) * 68 + r] = v.x;
            sX[(q * 4 + 1) * 68 + r] = v.y;
            sX[(q * 4 + 2) * 68 + r] = v.z;
            sX[(q * 4 + 3) * 68 + r] = v.w;
        }
    }
    __syncthreads();

    int tx = tid & 7;
    int ty = tid >> 3;
    float acc[2][4];
#pragma unroll
    for (int i = 0; i < 2; i++)
#pragma unroll
        for (int j = 0; j < 4; j++) acc[i][j] = 0.0f;

#pragma unroll 4
    for (int k = 0; k < 128; k++) {
        float a0 = sX[k * 68 + ty * 2];
        float a1 = sX[k * 68 + ty * 2 + 1];
        float4 wv = *(const float4*)&sW[k * 32 + tx * 4];
#pragma unroll
        for (int j = 0; j < 4; j++) {
            float w = (&wv.x)[j];
            acc[0][j] += a0 * w;
            acc[1][j] += a1 * w;
        }
    }
    __syncthreads();

    float hv[2][4];
#pragma unroll
    for (int i = 0; i < 2; i++) {
        int node = node0 + ty * 2 + i;
#pragma unroll
        for (int j = 0; j < 4; j++) {
            hv[i][j] = acc[i][j] + sb1[tx * 4 + j];
            sX[(tx * 4 + j) * 68 + (ty * 2 + i)] = hv[i][j];
        }
        if (node < n) {
            float4 o = make_float4(hv[i][0], hv[i][1], hv[i][2], hv[i][3]);
            *(float4*)&h[(size_t)node * 32 + tx * 4] = o;
        }
    }
    for (int i = tid; i < 32 * 64; i += 256) sW[i] = W2[i];
    __syncthreads();

    int tx2 = tid & 15;
    int ty2 = tid >> 4;
    float acc2[4][4];
#pragma unroll
    for (int i = 0; i < 4; i++)
#pragma unroll
        for (int j = 0; j < 4; j++) acc2[i][j] = 0.0f;

#pragma unroll 4
    for (int k = 0; k < 32; k++) {
        float4 av = *(const float4*)&sX[k * 68 + ty2 * 4];
        float4 wv = *(const float4*)&sW[k * 64 + tx2 * 4];
        float a_[4] = {av.x, av.y, av.z, av.w};
#pragma unroll
        for (int i = 0; i < 4; i++)
#pragma unroll
            for (int j = 0; j < 4; j++)
                acc2[i][j] += a_[i] * (&wv.x)[j];
    }
#pragma unroll
    for (int i = 0; i < 4; i++) {
        int node = node0 + ty2 * 4 + i;
        if (node >= n) continue;
        float4 o;
        o.x = gelu_tanh(acc2[i][0] + sb2[tx2 * 4]);
        o.y = gelu_tanh(acc2[i][1] + sb2[tx2 * 4 + 1]);
        o.z = gelu_tanh(acc2[i][2] + sb2[tx2 * 4 + 2]);
        o.w = gelu_tanh(acc2[i][3] + sb2[tx2 * 4 + 3]);
        *(float4*)&m[(size_t)node * 64 + tx2 * 4] = o;
    }
}

// agg[node] = sum over in-edges of m[src] (fp32 rows, x4 unroll)
__global__ void k_gather64(const int* __restrict__ row_ptr, const int* __restrict__ csr_src,
                           const float* __restrict__ m, float* __restrict__ agg, int n) {
    int wave = (blockIdx.x * blockDim.x + threadIdx.x) >> 6;
    int f = threadIdx.x & 63;
    if (wave >= n) return;
    int beg = row_ptr[wave], end = row_ptr[wave + 1];
    float acc = 0.0f;
    int p = beg;
    for (; p + 3 < end; p += 4) {
        int s0 = csr_src[p], s1 = csr_src[p + 1], s2 = csr_src[p + 2], s3 = csr_src[p + 3];
        float a = m[(size_t)s0 * 64 + f];
        float b = m[(size_t)s1 * 64 + f];
        float c = m[(size_t)s2 * 64 + f];
        float d = m[(size_t)s3 * 64 + f];
        acc += (a + b) + (c + d);
    }
    for (; p < end; p++) acc += m[(size_t)csr_src[p] * 64 + f];
    agg[(size_t)wave * 64 + f] = acc;
}

// m_out = gelu(m_in @ Ws + agg @ Wn). If w2 != null: fused params+rotate.
__global__ __launch_bounds__(256) void k_gnn(const float* m_in, const float* __restrict__ agg,
                      const float* __restrict__ Ws, const float* __restrict__ Wn,
                      float* m_out,
                      const float* w2, const float* b2, const int* row_ptr,
                      const float* xs, float4* params, bf16_t* ysh, int n) {
    __shared__ float sWs[64 * 64];
    __shared__ float sWn[64 * 64];
    __shared__ float sA[64 * 68];
    __shared__ float sw2[64];
    int tid = threadIdx.x;
    for (int i = tid; i < 64 * 64; i += 256) { sWs[i] = Ws[i]; sWn[i] = Wn[i]; }
    if (w2 && tid < 64) sw2[tid] = w2[tid];
    int node0 = blockIdx.x * 64;
    int tx = tid & 15;
    int ty = tid >> 4;
    float acc[4][4];
#pragma unroll
    for (int i = 0; i < 4; i++)
#pragma unroll
        for (int j = 0; j < 4; j++) acc[i][j] = 0.0f;

#pragma unroll
    for (int phase = 0; phase < 2; phase++) {
        const float* A = phase ? agg : m_in;
        __syncthreads();
        int r0 = tid >> 6;
        int c = tid & 63;
#pragma unroll
        for (int rr = 0; rr < 16; rr++) {
            int r = rr * 4 + r0;
            int node = node0 + r;
            float v = (node < n) ? A[(size_t)node * 64 + c] : 0.0f;
            sA[c * 68 + r] = v;
        }
        __syncthreads();
        const float* w = phase ? sWn : sWs;
#pragma unroll 4
        for (int k = 0; k < 64; k++) {
            float4 av = *(const float4*)&sA[k * 68 + ty * 4];
            float4 wv = *(const float4*)&w[k * 64 + tx * 4];
            float a_[4] = {av.x, av.y, av.z, av.w};
#pragma unroll
            for (int i = 0; i < 4; i++)
#pragma unroll
                for (int j = 0; j < 4; j++)
                    acc[i][j] += a_[i] * (&wv.x)[j];
        }
    }
    float o[4][4];
#pragma unroll
    for (int i = 0; i < 4; i++) {
        int node = node0 + ty * 4 + i;
#pragma unroll
        for (int j = 0; j < 4; j++) o[i][j] = gelu_tanh(acc[i][j]);
        if (node < n) {
            float4 ov = make_float4(o[i][0], o[i][1], o[i][2], o[i][3]);
            *(float4*)&m_out[(size_t)node * 64 + tx * 4] = ov;
        }
    }
    if (!w2) return;

    // ---- fused params + rotate epilogue ----
    __syncthreads();
#pragma unroll
    for (int i = 0; i < 4; i++) {
        int nl = ty * 4 + i;
#pragma unroll
        for (int j = 0; j < 4; j++) sA[nl * 68 + tx * 4 + j] = o[i][j];
    }
    __syncthreads();
    if (tid < 64) {
        int node = node0 + tid;
        if (node < n) {
            float acc2 = b2[0];
#pragma unroll 8
            for (int k = 0; k < 64; k++) acc2 += sA[tid * 68 + k] * sw2[k];
            float theta = tanhf(acc2);
            float ang = 6.283185307179586f * theta;
            float c = cosf(ang), s = sinf(ang);
            float deg = (float)(row_ptr[node + 1] - row_ptr[node]);
            float rd = rsqrtf(deg + 1.0f);
            params[node] = make_float4(c, s, rd, 0.0f);
            const float4* xr = (const float4*)(xs + (size_t)node * 32);
            ushort4* yr = (ushort4*)(ysh + (size_t)node * 32);
#pragma unroll
            for (int q = 0; q < 4; q++) {
                float4 x0 = xr[q];
                float4 x1 = xr[q + 4];
                float y0[4], y1[4];
                float x0_[4] = {x0.x, x0.y, x0.z, x0.w};
                float x1_[4] = {x1.x, x1.y, x1.z, x1.w};
#pragma unroll
                for (int t = 0; t < 4; t++) {
                    y0[t] = rd * (c * x0_[t] - s * x1_[t]);
                    y1[t] = rd * (s * x0_[t] + c * x1_[t]);
                }
                yr[q]     = make_ushort4(f2bf(y0[0]), f2bf(y0[1]), f2bf(y0[2]), f2bf(y0[3]));
                yr[q + 4] = make_ushort4(f2bf(y1[0]), f2bf(y1[1]), f2bf(y1[2]), f2bf(y1[3]));
            }
        }
    }
}

// S[node] = sum over in-edges of ysh[src] (bf16 rows = 1 line, 2 edges/wave)
__global__ void k_gather32(const int* __restrict__ row_ptr, const int* __restrict__ csr_src,
                           const bf16_t* __restrict__ ysh, float* __restrict__ S, int n) {
    int wave = (blockIdx.x * blockDim.x + threadIdx.x) >> 6;
    int lane = threadIdx.x & 63;
    int f = lane & 31;
    int half = lane >> 5;
    if (wave >= n) return;
    int beg = row_ptr[wave], end = row_ptr[wave + 1];
    float acc = 0.0f;
    int p = beg + half;
    for (; p + 2 < end; p += 4) {
        int s0 = csr_src[p], s1 = csr_src[p + 2];
        float a = bf2f(ysh[(size_t)s0 * 32 + f]);
        float b = bf2f(ysh[(size_t)s1 * 32 + f]);
        acc += a + b;
    }
    if (p < end) acc += bf2f(ysh[(size_t)csr_src[p] * 32 + f]);
    acc += __shfl_xor(acc, 32, 64);
    if (half == 0) S[(size_t)wave * 32 + f] = acc;
}

// xs = xs - gelu((xs - rd*R(-th)*S) @ Wd); also emits ysh for the next layer.
__global__ __launch_bounds__(256, 2) void k_update_mid(
                             float* __restrict__ xs, const float* __restrict__ S,
                             const float4* __restrict__ params, const float* __restrict__ Wd,
                             bf16_t* __restrict__ ysh, int n) {
    __shared__ float sW[256];
    for (int i = threadIdx.x; i < 256; i += blockDim.x) sW[i] = Wd[i];
    __syncthreads();
    int node = blockIdx.x * blockDim.x + threadIdx.x;
    if (node >= n) return;
    float4 pd = params[node];
    float cd = pd.x, sd = pd.y, rd = pd.z;
    float* xrow = xs + (size_t)node * 32;
    const float* srow = S + (size_t)node * 32;
    float a0[16], a1[16];
#pragma unroll
    for (int i = 0; i < 4; i++) {
        float4 s0 = ((const float4*)srow)[i];
        float4 s1 = ((const float4*)(srow + 16))[i];
        float s0_[4] = {s0.x, s0.y, s0.z, s0.w};
        float s1_[4] = {s1.x, s1.y, s1.z, s1.w};
#pragma unroll
        for (int t = 0; t < 4; t++) {
            a0[4 * i + t] = rd * (cd * s0_[t] + sd * s1_[t]);
            a1[4 * i + t] = rd * (cd * s1_[t] - sd * s0_[t]);
        }
    }
    float nx0[16], nx1[16];
#pragma unroll
    for (int dd = 0; dd < 2; dd++) {
        const float* av = dd ? a1 : a0;
        float* nx = dd ? nx1 : nx0;
        float xr[16], lx[16];
        const float4* x4 = (const float4*)(xrow + dd * 16);
#pragma unroll
        for (int i = 0; i < 4; i++) {
            float4 v = x4[i];
            xr[4 * i] = v.x; xr[4 * i + 1] = v.y; xr[4 * i + 2] = v.z; xr[4 * i + 3] = v.w;
            lx[4 * i] = v.x - av[4 * i];
            lx[4 * i + 1] = v.y - av[4 * i + 1];
            lx[4 * i + 2] = v.z - av[4 * i + 2];
            lx[4 * i + 3] = v.w - av[4 * i + 3];
        }
#pragma unroll
        for (int j = 0; j < 16; j++) {
            float acc = 0.0f;
#pragma unroll
            for (int k = 0; k < 16; k++) acc += lx[k] * sW[k * 16 + j];
            nx[j] = xr[j] - gelu_tanh(acc);
        }
    }
    float4* xo = (float4*)xrow;
    ushort4* yr = (ushort4*)(ysh + (size_t)node * 32);
#pragma unroll
    for (int q = 0; q < 4; q++) {
        xo[q]     = make_float4(nx0[4 * q], nx0[4 * q + 1], nx0[4 * q + 2], nx0[4 * q + 3]);
        xo[q + 4] = make_float4(nx1[4 * q], nx1[4 * q + 1], nx1[4 * q + 2], nx1[4 * q + 3]);
        float y0[4], y1[4];
#pragma unroll
        for (int t = 0; t < 4; t++) {
            y0[t] = rd * (cd * nx0[4 * q + t] - sd * nx1[4 * q + t]);
            y1[t] = rd * (sd * nx0[4 * q + t] + cd * nx1[4 * q + t]);
        }
        yr[q]     = make_ushort4(f2bf(y0[0]), f2bf(y0[1]), f2bf(y0[2]), f2bf(y0[3]));
        yr[q + 4] = make_ushort4(f2bf(y1[0]), f2bf(y1[1]), f2bf(y1[2]), f2bf(y1[3]));
    }
}

// final layer: update + output projection fused; xs never written back.
__global__ __launch_bounds__(256, 2) void k_update_out(
                             const float* __restrict__ xs, const float* __restrict__ S,
                             const float4* __restrict__ params, const float* __restrict__ Wd,
                             const float* __restrict__ Wo, const float* __restrict__ bo,
                             float* __restrict__ out, int n) {
    __shared__ float sW[256];
    __shared__ float sWo[320];
    __shared__ float sbo[10];
    for (int i = threadIdx.x; i < 256; i += blockDim.x) sW[i] = Wd[i];
    for (int i = threadIdx.x; i < 320; i += blockDim.x) sWo[i] = Wo[i];
    for (int i = threadIdx.x; i < 10; i += blockDim.x) sbo[i] = bo[i];
    __syncthreads();
    int node = blockIdx.x * blockDim.x + threadIdx.x;
    if (node >= n) return;
    float4 pd = params[node];
    float cd = pd.x, sd = pd.y, rd = pd.z;
    const float* xrow = xs + (size_t)node * 32;
    const float* srow = S + (size_t)node * 32;
    float a0[16], a1[16];
#pragma unroll
    for (int i = 0; i < 4; i++) {
        float4 s0 = ((const float4*)srow)[i];
        float4 s1 = ((const float4*)(srow + 16))[i];
        float s0_[4] = {s0.x, s0.y, s0.z, s0.w};
        float s1_[4] = {s1.x, s1.y, s1.z, s1.w};
#pragma unroll
        for (int t = 0; t < 4; t++) {
            a0[4 * i + t] = rd * (cd * s0_[t] + sd * s1_[t]);
            a1[4 * i + t] = rd * (cd * s1_[t] - sd * s0_[t]);
        }
    }
    float nx[32];
#pragma unroll
    for (int dd = 0; dd < 2; dd++) {
        const float* av = dd ? a1 : a0;
        float xr[16], lx[16];
        const float4* x4 = (const float4*)(xrow + dd * 16);
#pragma unroll
        for (int i = 0; i < 4; i++) {
            float4 v = x4[i];
            xr[4 * i] = v.x; xr[4 * i + 1] = v.y; xr[4 * i + 2] = v.z; xr[4 * i + 3] = v.w;
            lx[4 * i] = v.x - av[4 * i];
            lx[4 * i + 1] = v.y - av[4 * i + 1];
            lx[4 * i + 2] = v.z - av[4 * i + 2];
            lx[4 * i + 3] = v.w - av[4 * i + 3];
        }
#pragma unroll
        for (int j = 0; j < 16; j++) {
            float acc = 0.0f;
#pragma unroll
            for (int k = 0; k < 16; k++) acc += lx[k] * sW[k * 16 + j];
            nx[dd * 16 + j] = xr[j] - gelu_tanh(acc);
        }
    }
    float* orow = out + (size_t)node * 10;
#pragma unroll
    for (int j = 0; j < 10; j++) {
        float acc = sbo[j];
#pragma unroll
        for (int k = 0; k < 32; k++) acc += nx[k] * sWo[k * 10 + j];
        orow[j] = acc;
    }
}

static inline size_t align256(size_t x) { return (x + 255) & ~(size_t)255; }

extern "C" void kernel_launch(void* const* d_in, const int* in_sizes, int n_in,
                              void* d_out, int out_size, void* d_ws, size_t ws_size,
                              hipStream_t stream) {
    const float* x      = (const float*)d_in[0];
    const int*   ei     = (const int*)d_in[1];
    const float* W_in   = (const float*)d_in[2];
    const float* b_in   = (const float*)d_in[3];
    const float* emb1_W = (const float*)d_in[4];
    const float* emb1_b = (const float*)d_in[5];
    const float* Ws1    = (const float*)d_in[6];
    const float* Wn1    = (const float*)d_in[7];
    const float* Ws2    = (const float*)d_in[8];
    const float* Wn2    = (const float*)d_in[9];
    const float* emb2_W = (const float*)d_in[10];
    const float* emb2_b = (const float*)d_in[11];
    const float* W_diff = (const float*)d_in[12];
    const float* W_out  = (const float*)d_in[13];
    const float* b_out  = (const float*)d_in[14];

    int n = in_sizes[0] / 128;  // 100000
    int e = in_sizes[1] / 2;    // 1600000
    int nt = (n + 255) / 256;
    int sn = (n + NSHARD - 1) / NSHARD;   // nodes per shard (<=1024 required)

    char* base = (char*)d_ws;
    size_t off = 0;
    int*    csr_src = (int*)(base + off);    off = align256(off + (size_t)e * 4);
    int2*   ebuf    = (int2*)(base + off);   off = align256(off + (size_t)e * 8);
    int*    row_ptr = (int*)(base + off);    off = align256(off + (size_t)(n + 1) * 4);
    int*    cnt     = (int*)(base + off);    off = align256(off + (size_t)n * 4);
    int*    bcur    = (int*)(base + off);    off = align256(off + NSHARD * 4);
    int*    bsums   = (int*)(base + off);    off = align256(off + (size_t)nt * 4);
    int*    flag    = (int*)(base + off);    off = align256(off + 16);
    float*  h       = (float*)(base + off);  off = align256(off + (size_t)n * 32 * 4);
    float*  m       = (float*)(base + off);  off = align256(off + (size_t)n * 64 * 4);
    bf16_t* ysh     = (bf16_t*)(base + off); off = align256(off + (size_t)n * 32 * 2);
    float*  agg     = (float*)(base + off);  off = align256(off + (size_t)n * 64 * 4);
    float4* params  = (float4*)(base + off);

    int nb = (n + 255) / 256;
    int eb = (e + 255) / 256;
    int tb64 = (n + 63) / 64;
    int pb = (e + CHUNK - 1) / CHUNK;

    // CSR build: hist -> scan -> bulk-reserved partition -> LDS distribute
    k_detect<<<1, 64, 0, stream>>>(ei, flag);
    hipMemsetAsync(cnt, 0, (size_t)n * 4, stream);
    k_hist<<<eb, 256, 0, stream>>>(ei, flag, cnt, e);
    k_scan1<<<nt, 256, 0, stream>>>(cnt, row_ptr, bsums, n);
    k_scan2<<<1, 1024, 0, stream>>>(bsums, nt);
    k_scan3<<<nt, 256, 0, stream>>>(row_ptr, bsums, n);
    k_binit<<<1, NSHARD, 0, stream>>>(row_ptr, bcur, sn, n);
    k_partition<<<pb, 256, 0, stream>>>(ei, flag, bcur, ebuf, e, sn);
    k_distribute<<<NSHARD, 256, 0, stream>>>(row_ptr, ebuf, csr_src, sn, n);

    // fused embeddings
    k_embed_hm<<<tb64, 256, 0, stream>>>(x, W_in, b_in, emb1_W, emb1_b, h, m, n);

    // sheaf learner GNN layers; gnn #2 fuses params + first rotate
    int gb64 = (n * 64 + 255) / 256;
    k_gather64<<<gb64, 256, 0, stream>>>(row_ptr, csr_src, m, agg, n);
    k_gnn<<<tb64, 256, 0, stream>>>(m, agg, Ws1, Wn1, m,
                                    nullptr, nullptr, nullptr, nullptr, nullptr, nullptr, n);
    k_gather64<<<gb64, 256, 0, stream>>>(row_ptr, csr_src, m, agg, n);
    k_gnn<<<tb64, 256, 0, stream>>>(m, agg, Ws2, Wn2, m,
                                    emb2_W, emb2_b, row_ptr, h, params, ysh, n);

    // diffusion: gather -> update(+rotate) -> gather -> update(+out)
    k_gather32<<<gb64, 256, 0, stream>>>(row_ptr, csr_src, ysh, agg, n);
    k_update_mid<<<nb, 256, 0, stream>>>(h, agg, params, W_diff, ysh, n);
    k_gather32<<<gb64, 256, 0, stream>>>(row_ptr, csr_src, ysh, agg, n);
    k_update_out<<<nb, 256, 0, stream>>>(h, agg, params, W_diff + 256,
                                         W_out, b_out, (float*)d_out, n);
}

// Round 16
// 693.410 us; speedup vs baseline: 1.1846x; 1.0789x over previous
//
#include <hip/hip_runtime.h>
#include <math.h>

// ---------------------------------------------------------------------------
// SheafDiffusion on MI355X — round 15: CSR build v3. Shard-level count (one
// global atomic per block x shard) + in-LDS per-shard node histogram/scan in
// k_distribute (row_ptr computed there). Eliminates k_hist (1.6M random
// atomics), k_scan1/2/3, and the n-word memset. NSHARD 128->256.
// ---------------------------------------------------------------------------

typedef unsigned short bf16_t;

#define NSHARD 256
#define CHUNK 4096

__device__ __forceinline__ float bf2f(bf16_t u) {
    return __uint_as_float(((unsigned int)u) << 16);
}
__device__ __forceinline__ bf16_t f2bf(float f) {
    unsigned int u = __float_as_uint(f);
    unsigned int r = (u + 0x7FFFu + ((u >> 16) & 1u)) >> 16;  // RNE
    return (bf16_t)r;
}

__device__ __forceinline__ float gelu_tanh(float x) {
    float x3 = x * x * x;
    float t = tanhf(0.7978845608028654f * (x + 0.044715f * x3));
    return 0.5f * x * (1.0f + t);
}

// ---- edge dtype detection ------------------------------------------------
__global__ void k_detect(const int* __restrict__ ei, int* __restrict__ flag) {
    if (blockIdx.x == 0 && threadIdx.x == 0) {
        int is64 = 1;
        for (int i = 1; i < 256; i += 2)
            if (ei[i] != 0) { is64 = 0; break; }
        *flag = is64;
    }
}

// ---- CSR build v3 --------------------------------------------------------
// shard-level histogram: one global atomic per (block, shard)
__global__ __launch_bounds__(256) void k_count(const int* __restrict__ ei,
                        const int* __restrict__ flag, int* __restrict__ shard_cnt,
                        int e, int sn) {
    __shared__ int lc[NSHARD];
    if (threadIdx.x < NSHARD) lc[threadIdx.x] = 0;
    __syncthreads();
    int is64 = *flag;
    int beg = blockIdx.x * CHUNK;
    int end = min(beg + CHUNK, e);
    for (int i = beg + threadIdx.x; i < end; i += 256) {
        int d = is64 ? ei[2 * (e + i)] : ei[e + i];
        atomicAdd(&lc[d / sn], 1);
    }
    __syncthreads();
    if (threadIdx.x < NSHARD) {
        int c = lc[threadIdx.x];
        if (c) atomicAdd(&shard_cnt[threadIdx.x], c);
    }
}

// single-block exclusive scan of shard counts -> shard_base[257], bcur init
__global__ void k_scan_shard(const int* __restrict__ shard_cnt,
                             int* __restrict__ shard_base, int* __restrict__ bcur) {
    __shared__ int s[NSHARD];
    int t = threadIdx.x;
    s[t] = shard_cnt[t];
    __syncthreads();
#pragma unroll
    for (int off = 1; off < NSHARD; off <<= 1) {
        int add = (t >= off) ? s[t - off] : 0;
        __syncthreads();
        s[t] += add;
        __syncthreads();
    }
    int excl = (t == 0) ? 0 : s[t - 1];
    shard_base[t] = excl;
    bcur[t] = excl;
    if (t == NSHARD - 1) shard_base[NSHARD] = s[t];
}

// phase 1: partition edges into shard regions of ebuf with bulk reservation
__global__ __launch_bounds__(256) void k_partition(const int* __restrict__ ei,
                        const int* __restrict__ flag, int* __restrict__ bcur,
                        int2* __restrict__ ebuf, int e, int sn) {
    __shared__ int lcnt[NSHARD];
    __shared__ int lbase[NSHARD];
    int is64 = *flag;
    int beg = blockIdx.x * CHUNK;
    int end = min(beg + CHUNK, e);
    if (threadIdx.x < NSHARD) lcnt[threadIdx.x] = 0;
    __syncthreads();
    for (int i = beg + threadIdx.x; i < end; i += 256) {
        int d = is64 ? ei[2 * (e + i)] : ei[e + i];
        atomicAdd(&lcnt[d / sn], 1);
    }
    __syncthreads();
    if (threadIdx.x < NSHARD) {
        int c = lcnt[threadIdx.x];
        lbase[threadIdx.x] = (c > 0) ? atomicAdd(&bcur[threadIdx.x], c) : 0;
        lcnt[threadIdx.x] = 0;
    }
    __syncthreads();
    for (int i = beg + threadIdx.x; i < end; i += 256) {
        int d = is64 ? ei[2 * (e + i)] : ei[e + i];
        int s = is64 ? ei[2 * i] : ei[i];
        int sh = d / sn;
        int pos = lbase[sh] + atomicAdd(&lcnt[sh], 1);
        ebuf[pos] = make_int2(s, d);
    }
}

// phase 2: one block per shard. Computes row_ptr (LDS node hist + scan) and
// places edges into the shard's contiguous csr window.
__global__ __launch_bounds__(256) void k_distribute(const int* __restrict__ shard_base,
                        const int2* __restrict__ ebuf, int* __restrict__ csr_src,
                        int* __restrict__ row_ptr, int sn, int n) {
    __shared__ int lcnt[512];   // sn <= 512
    __shared__ int lcur[512];
    __shared__ int stmp[256];
    int sh = blockIdx.x;
    int node0 = sh * sn;
    if (node0 >= n) return;
    int nloc = min(sn, n - node0);
    int base = shard_base[sh];
    int bend = shard_base[sh + 1];
    for (int j = threadIdx.x; j < nloc; j += 256) lcnt[j] = 0;
    __syncthreads();
    // node-level histogram
    for (int p = base + threadIdx.x; p < bend; p += 256) {
        int2 ed = ebuf[p];
        atomicAdd(&lcnt[ed.y - node0], 1);
    }
    __syncthreads();
    // block-wide exclusive scan with carry; emit row_ptr
    int carry = 0;
    for (int seg = 0; seg < nloc; seg += 256) {
        int idx = seg + threadIdx.x;
        int v = (idx < nloc) ? lcnt[idx] : 0;
        stmp[threadIdx.x] = v;
        __syncthreads();
#pragma unroll
        for (int off = 1; off < 256; off <<= 1) {
            int add = (threadIdx.x >= off) ? stmp[threadIdx.x - off] : 0;
            __syncthreads();
            stmp[threadIdx.x] += add;
            __syncthreads();
        }
        int incl = stmp[threadIdx.x];
        if (idx < nloc) {
            lcur[idx] = base + carry + incl - v;          // exclusive cursor
            row_ptr[node0 + idx + 1] = base + carry + incl;
        }
        carry += stmp[255];
        __syncthreads();   // protect stmp before next segment
    }
    if (sh == 0 && threadIdx.x == 0) row_ptr[0] = 0;
    __syncthreads();
    // place
    for (int p = base + threadIdx.x; p < bend; p += 256) {
        int2 ed = ebuf[p];
        int pos = atomicAdd(&lcur[ed.y - node0], 1);
        csr_src[pos] = ed.x;
    }
}

// ---- fused embedding: h = x@W_in+b ; m = gelu(h@emb1_W+emb1_b) ------------
__global__ __launch_bounds__(256) void k_embed_hm(const float* __restrict__ x,
                          const float* __restrict__ W_in, const float* __restrict__ b_in,
                          const float* __restrict__ W2, const float* __restrict__ b2,
                          float* __restrict__ h, float* __restrict__ m, int n) {
    __shared__ float sW[128 * 32];
    __shared__ float sX[128 * 68];
    __shared__ float sb1[32];
    __shared__ float sb2[64];
    int tid = threadIdx.x;
    for (int i = tid; i < 128 * 32; i += 256) sW[i] = W_in[i];
    for (int i = tid; i < 32; i += 256) sb1[i] = b_in[i];
    for (int i = tid; i < 64; i += 256) sb2[i] = b2[i];

    int node0 = blockIdx.x * 64;
    {
        int r = tid >> 2;
        int q0 = tid & 3;
        int node_r = node0 + r;
        const float4* xrow = (const float4*)(x + (size_t)node_r * 128);
#pragma unroll
        for (int qq = 0; qq < 8; qq++) {
            int q = qq * 4 + q0;
            float4 v = (node_r < n) ? xrow[q] : make_float4(0.f, 0.f, 0.f, 0.f);
            sX[(q * 4 + 0) * 68 + r] = v.x;
            sX[(q * 4 + 1) * 68 + r] = v.y;
            sX[(q * 4 + 2) * 68 + r] = v.z;
            sX[(q * 4 + 3) * 68 + r] = v.w;
        }
    }
    __syncthreads();

    int tx = tid & 7;
    int ty = tid >> 3;
    float acc[2][4];
#pragma unroll
    for (int i = 0; i < 2; i++)
#pragma unroll
        for (int j = 0; j < 4; j++) acc[i][j] = 0.0f;

#pragma unroll 4
    for (int k = 0; k < 128; k++) {
        float a0 = sX[k * 68 + ty * 2];
        float a1 = sX[k * 68 + ty * 2 + 1];
        float4 wv = *(const float4*)&sW[k * 32 + tx * 4];
#pragma unroll
        for (int j = 0; j < 4; j++) {
            float w = (&wv.x)[j];
            acc[0][j] += a0 * w;
            acc[1][j] += a1 * w;
        }
    }
    __syncthreads();

    float hv[2][4];
#pragma unroll
    for (int i = 0; i < 2; i++) {
        int node = node0 + ty * 2 + i;
#pragma unroll
        for (int j = 0; j < 4; j++) {
            hv[i][j] = acc[i][j] + sb1[tx * 4 + j];
            sX[(tx * 4 + j) * 68 + (ty * 2 + i)] = hv[i][j];
        }
        if (node < n) {
            float4 o = make_float4(hv[i][0], hv[i][1], hv[i][2], hv[i][3]);
            *(float4*)&h[(size_t)node * 32 + tx * 4] = o;
        }
    }
    for (int i = tid; i < 32 * 64; i += 256) sW[i] = W2[i];
    __syncthreads();

    int tx2 = tid & 15;
    int ty2 = tid >> 4;
    float acc2[4][4];
#pragma unroll
    for (int i = 0; i < 4; i++)
#pragma unroll
        for (int j = 0; j < 4; j++) acc2[i][j] = 0.0f;

#pragma unroll 4
    for (int k = 0; k < 32; k++) {
        float4 av = *(const float4*)&sX[k * 68 + ty2 * 4];
        float4 wv = *(const float4*)&sW[k * 64 + tx2 * 4];
        float a_[4] = {av.x, av.y, av.z, av.w};
#pragma unroll
        for (int i = 0; i < 4; i++)
#pragma unroll
            for (int j = 0; j < 4; j++)
                acc2[i][j] += a_[i] * (&wv.x)[j];
    }
#pragma unroll
    for (int i = 0; i < 4; i++) {
        int node = node0 + ty2 * 4 + i;
        if (node >= n) continue;
        float4 o;
        o.x = gelu_tanh(acc2[i][0] + sb2[tx2 * 4]);
        o.y = gelu_tanh(acc2[i][1] + sb2[tx2 * 4 + 1]);
        o.z = gelu_tanh(acc2[i][2] + sb2[tx2 * 4 + 2]);
        o.w = gelu_tanh(acc2[i][3] + sb2[tx2 * 4 + 3]);
        *(float4*)&m[(size_t)node * 64 + tx2 * 4] = o;
    }
}

// agg[node] = sum over in-edges of m[src] (fp32 rows, x4 unroll)
__global__ void k_gather64(const int* __restrict__ row_ptr, const int* __restrict__ csr_src,
                           const float* __restrict__ m, float* __restrict__ agg, int n) {
    int wave = (blockIdx.x * blockDim.x + threadIdx.x) >> 6;
    int f = threadIdx.x & 63;
    if (wave >= n) return;
    int beg = row_ptr[wave], end = row_ptr[wave + 1];
    float acc = 0.0f;
    int p = beg;
    for (; p + 3 < end; p += 4) {
        int s0 = csr_src[p], s1 = csr_src[p + 1], s2 = csr_src[p + 2], s3 = csr_src[p + 3];
        float a = m[(size_t)s0 * 64 + f];
        float b = m[(size_t)s1 * 64 + f];
        float c = m[(size_t)s2 * 64 + f];
        float d = m[(size_t)s3 * 64 + f];
        acc += (a + b) + (c + d);
    }
    for (; p < end; p++) acc += m[(size_t)csr_src[p] * 64 + f];
    agg[(size_t)wave * 64 + f] = acc;
}

// m_out = gelu(m_in @ Ws + agg @ Wn). If w2 != null: fused params+rotate.
__global__ __launch_bounds__(256) void k_gnn(const float* m_in, const float* __restrict__ agg,
                      const float* __restrict__ Ws, const float* __restrict__ Wn,
                      float* m_out,
                      const float* w2, const float* b2, const int* row_ptr,
                      const float* xs, float4* params, bf16_t* ysh, int n) {
    __shared__ float sWs[64 * 64];
    __shared__ float sWn[64 * 64];
    __shared__ float sA[64 * 68];
    __shared__ float sw2[64];
    int tid = threadIdx.x;
    for (int i = tid; i < 64 * 64; i += 256) { sWs[i] = Ws[i]; sWn[i] = Wn[i]; }
    if (w2 && tid < 64) sw2[tid] = w2[tid];
    int node0 = blockIdx.x * 64;
    int tx = tid & 15;
    int ty = tid >> 4;
    float acc[4][4];
#pragma unroll
    for (int i = 0; i < 4; i++)
#pragma unroll
        for (int j = 0; j < 4; j++) acc[i][j] = 0.0f;

#pragma unroll
    for (int phase = 0; phase < 2; phase++) {
        const float* A = phase ? agg : m_in;
        __syncthreads();
        int r0 = tid >> 6;
        int c = tid & 63;
#pragma unroll
        for (int rr = 0; rr < 16; rr++) {
            int r = rr * 4 + r0;
            int node = node0 + r;
            float v = (node < n) ? A[(size_t)node * 64 + c] : 0.0f;
            sA[c * 68 + r] = v;
        }
        __syncthreads();
        const float* w = phase ? sWn : sWs;
#pragma unroll 4
        for (int k = 0; k < 64; k++) {
            float4 av = *(const float4*)&sA[k * 68 + ty * 4];
            float4 wv = *(const float4*)&w[k * 64 + tx * 4];
            float a_[4] = {av.x, av.y, av.z, av.w};
#pragma unroll
            for (int i = 0; i < 4; i++)
#pragma unroll
                for (int j = 0; j < 4; j++)
                    acc[i][j] += a_[i] * (&wv.x)[j];
        }
    }
    float o[4][4];
#pragma unroll
    for (int i = 0; i < 4; i++) {
        int node = node0 + ty * 4 + i;
#pragma unroll
        for (int j = 0; j < 4; j++) o[i][j] = gelu_tanh(acc[i][j]);
        if (node < n) {
            float4 ov = make_float4(o[i][0], o[i][1], o[i][2], o[i][3]);
            *(float4*)&m_out[(size_t)node * 64 + tx * 4] = ov;
        }
    }
    if (!w2) return;

    // ---- fused params + rotate epilogue ----
    __syncthreads();
#pragma unroll
    for (int i = 0; i < 4; i++) {
        int nl = ty * 4 + i;
#pragma unroll
        for (int j = 0; j < 4; j++) sA[nl * 68 + tx * 4 + j] = o[i][j];
    }
    __syncthreads();
    if (tid < 64) {
        int node = node0 + tid;
        if (node < n) {
            float acc2 = b2[0];
#pragma unroll 8
            for (int k = 0; k < 64; k++) acc2 += sA[tid * 68 + k] * sw2[k];
            float theta = tanhf(acc2);
            float ang = 6.283185307179586f * theta;
            float c = cosf(ang), s = sinf(ang);
            float deg = (float)(row_ptr[node + 1] - row_ptr[node]);
            float rd = rsqrtf(deg + 1.0f);
            params[node] = make_float4(c, s, rd, 0.0f);
            const float4* xr = (const float4*)(xs + (size_t)node * 32);
            ushort4* yr = (ushort4*)(ysh + (size_t)node * 32);
#pragma unroll
            for (int q = 0; q < 4; q++) {
                float4 x0 = xr[q];
                float4 x1 = xr[q + 4];
                float y0[4], y1[4];
                float x0_[4] = {x0.x, x0.y, x0.z, x0.w};
                float x1_[4] = {x1.x, x1.y, x1.z, x1.w};
#pragma unroll
                for (int t = 0; t < 4; t++) {
                    y0[t] = rd * (c * x0_[t] - s * x1_[t]);
                    y1[t] = rd * (s * x0_[t] + c * x1_[t]);
                }
                yr[q]     = make_ushort4(f2bf(y0[0]), f2bf(y0[1]), f2bf(y0[2]), f2bf(y0[3]));
                yr[q + 4] = make_ushort4(f2bf(y1[0]), f2bf(y1[1]), f2bf(y1[2]), f2bf(y1[3]));
            }
        }
    }
}

// S[node] = sum over in-edges of ysh[src] (bf16 rows = 1 line, 2 edges/wave)
__global__ void k_gather32(const int* __restrict__ row_ptr, const int* __restrict__ csr_src,
                           const bf16_t* __restrict__ ysh, float* __restrict__ S, int n) {
    int wave = (blockIdx.x * blockDim.x + threadIdx.x) >> 6;
    int lane = threadIdx.x & 63;
    int f = lane & 31;
    int half = lane >> 5;
    if (wave >= n) return;
    int beg = row_ptr[wave], end = row_ptr[wave + 1];
    float acc = 0.0f;
    int p = beg + half;
    for (; p + 2 < end; p += 4) {
        int s0 = csr_src[p], s1 = csr_src[p + 2];
        float a = bf2f(ysh[(size_t)s0 * 32 + f]);
        float b = bf2f(ysh[(size_t)s1 * 32 + f]);
        acc += a + b;
    }
    if (p < end) acc += bf2f(ysh[(size_t)csr_src[p] * 32 + f]);
    acc += __shfl_xor(acc, 32, 64);
    if (half == 0) S[(size_t)wave * 32 + f] = acc;
}

// xs = xs - gelu((xs - rd*R(-th)*S) @ Wd); also emits ysh for the next layer.
__global__ __launch_bounds__(256, 2) void k_update_mid(
                             float* __restrict__ xs, const float* __restrict__ S,
                             const float4* __restrict__ params, const float* __restrict__ Wd,
                             bf16_t* __restrict__ ysh, int n) {
    __shared__ float sW[256];
    for (int i = threadIdx.x; i < 256; i += blockDim.x) sW[i] = Wd[i];
    __syncthreads();
    int node = blockIdx.x * blockDim.x + threadIdx.x;
    if (node >= n) return;
    float4 pd = params[node];
    float cd = pd.x, sd = pd.y, rd = pd.z;
    float* xrow = xs + (size_t)node * 32;
    const float* srow = S + (size_t)node * 32;
    float a0[16], a1[16];
#pragma unroll
    for (int i = 0; i < 4; i++) {
        float4 s0 = ((const float4*)srow)[i];
        float4 s1 = ((const float4*)(srow + 16))[i];
        float s0_[4] = {s0.x, s0.y, s0.z, s0.w};
        float s1_[4] = {s1.x, s1.y, s1.z, s1.w};
#pragma unroll
        for (int t = 0; t < 4; t++) {
            a0[4 * i + t] = rd * (cd * s0_[t] + sd * s1_[t]);
            a1[4 * i + t] = rd * (cd * s1_[t] - sd * s0_[t]);
        }
    }
    float nx0[16], nx1[16];
#pragma unroll
    for (int dd = 0; dd < 2; dd++) {
        const float* av = dd ? a1 : a0;
        float* nx = dd ? nx1 : nx0;
        float xr[16], lx[16];
        const float4* x4 = (const float4*)(xrow + dd * 16);
#pragma unroll
        for (int i = 0; i < 4; i++) {
            float4 v = x4[i];
            xr[4 * i] = v.x; xr[4 * i + 1] = v.y; xr[4 * i + 2] = v.z; xr[4 * i + 3] = v.w;
            lx[4 * i] = v.x - av[4 * i];
            lx[4 * i + 1] = v.y - av[4 * i + 1];
            lx[4 * i + 2] = v.z - av[4 * i + 2];
            lx[4 * i + 3] = v.w - av[4 * i + 3];
        }
#pragma unroll
        for (int j = 0; j < 16; j++) {
            float acc = 0.0f;
#pragma unroll
            for (int k = 0; k < 16; k++) acc += lx[k] * sW[k * 16 + j];
            nx[j] = xr[j] - gelu_tanh(acc);
        }
    }
    float4* xo = (float4*)xrow;
    ushort4* yr = (ushort4*)(ysh + (size_t)node * 32);
#pragma unroll
    for (int q = 0; q < 4; q++) {
        xo[q]     = make_float4(nx0[4 * q], nx0[4 * q + 1], nx0[4 * q + 2], nx0[4 * q + 3]);
        xo[q + 4] = make_float4(nx1[4 * q], nx1[4 * q + 1], nx1[4 * q + 2], nx1[4 * q + 3]);
        float y0[4], y1[4];
#pragma unroll
        for (int t = 0; t < 4; t++) {
            y0[t] = rd * (cd * nx0[4 * q + t] - sd * nx1[4 * q + t]);
            y1[t] = rd * (sd * nx0[4 * q + t] + cd * nx1[4 * q + t]);
        }
        yr[q]     = make_ushort4(f2bf(y0[0]), f2bf(y0[1]), f2bf(y0[2]), f2bf(y0[3]));
        yr[q + 4] = make_ushort4(f2bf(y1[0]), f2bf(y1[1]), f2bf(y1[2]), f2bf(y1[3]));
    }
}

// final layer: update + output projection fused; xs never written back.
__global__ __launch_bounds__(256, 2) void k_update_out(
                             const float* __restrict__ xs, const float* __restrict__ S,
                             const float4* __restrict__ params, const float* __restrict__ Wd,
                             const float* __restrict__ Wo, const float* __restrict__ bo,
                             float* __restrict__ out, int n) {
    __shared__ float sW[256];
    __shared__ float sWo[320];
    __shared__ float sbo[10];
    for (int i = threadIdx.x; i < 256; i += blockDim.x) sW[i] = Wd[i];
    for (int i = threadIdx.x; i < 320; i += blockDim.x) sWo[i] = Wo[i];
    for (int i = threadIdx.x; i < 10; i += blockDim.x) sbo[i] = bo[i];
    __syncthreads();
    int node = blockIdx.x * blockDim.x + threadIdx.x;
    if (node >= n) return;
    float4 pd = params[node];
    float cd = pd.x, sd = pd.y, rd = pd.z;
    const float* xrow = xs + (size_t)node * 32;
    const float* srow = S + (size_t)node * 32;
    float a0[16], a1[16];
#pragma unroll
    for (int i = 0; i < 4; i++) {
        float4 s0 = ((const float4*)srow)[i];
        float4 s1 = ((const float4*)(srow + 16))[i];
        float s0_[4] = {s0.x, s0.y, s0.z, s0.w};
        float s1_[4] = {s1.x, s1.y, s1.z, s1.w};
#pragma unroll
        for (int t = 0; t < 4; t++) {
            a0[4 * i + t] = rd * (cd * s0_[t] + sd * s1_[t]);
            a1[4 * i + t] = rd * (cd * s1_[t] - sd * s0_[t]);
        }
    }
    float nx[32];
#pragma unroll
    for (int dd = 0; dd < 2; dd++) {
        const float* av = dd ? a1 : a0;
        float xr[16], lx[16];
        const float4* x4 = (const float4*)(xrow + dd * 16);
#pragma unroll
        for (int i = 0; i < 4; i++) {
            float4 v = x4[i];
            xr[4 * i] = v.x; xr[4 * i + 1] = v.y; xr[4 * i + 2] = v.z; xr[4 * i + 3] = v.w;
            lx[4 * i] = v.x - av[4 * i];
            lx[4 * i + 1] = v.y - av[4 * i + 1];
            lx[4 * i + 2] = v.z - av[4 * i + 2];
            lx[4 * i + 3] = v.w - av[4 * i + 3];
        }
#pragma unroll
        for (int j = 0; j < 16; j++) {
            float acc = 0.0f;
#pragma unroll
            for (int k = 0; k < 16; k++) acc += lx[k] * sW[k * 16 + j];
            nx[dd * 16 + j] = xr[j] - gelu_tanh(acc);
        }
    }
    float* orow = out + (size_t)node * 10;
#pragma unroll
    for (int j = 0; j < 10; j++) {
        float acc = sbo[j];
#pragma unroll
        for (int k = 0; k < 32; k++) acc += nx[k] * sWo[k * 10 + j];
        orow[j] = acc;
    }
}

static inline size_t align256(size_t x) { return (x + 255) & ~(size_t)255; }

extern "C" void kernel_launch(void* const* d_in, const int* in_sizes, int n_in,
                              void* d_out, int out_size, void* d_ws, size_t ws_size,
                              hipStream_t stream) {
    const float* x      = (const float*)d_in[0];
    const int*   ei     = (const int*)d_in[1];
    const float* W_in   = (const float*)d_in[2];
    const float* b_in   = (const float*)d_in[3];
    const float* emb1_W = (const float*)d_in[4];
    const float* emb1_b = (const float*)d_in[5];
    const float* Ws1    = (const float*)d_in[6];
    const float* Wn1    = (const float*)d_in[7];
    const float* Ws2    = (const float*)d_in[8];
    const float* Wn2    = (const float*)d_in[9];
    const float* emb2_W = (const float*)d_in[10];
    const float* emb2_b = (const float*)d_in[11];
    const float* W_diff = (const float*)d_in[12];
    const float* W_out  = (const float*)d_in[13];
    const float* b_out  = (const float*)d_in[14];

    int n = in_sizes[0] / 128;  // 100000
    int e = in_sizes[1] / 2;    // 1600000
    int sn = (n + NSHARD - 1) / NSHARD;   // nodes per shard (<=512 required)

    char* base = (char*)d_ws;
    size_t off = 0;
    int*    csr_src   = (int*)(base + off);    off = align256(off + (size_t)e * 4);
    int2*   ebuf      = (int2*)(base + off);   off = align256(off + (size_t)e * 8);
    int*    row_ptr   = (int*)(base + off);    off = align256(off + (size_t)(n + 1) * 4);
    int*    shard_cnt = (int*)(base + off);    off = align256(off + NSHARD * 4);
    int*    shard_base= (int*)(base + off);    off = align256(off + (NSHARD + 1) * 4);
    int*    bcur      = (int*)(base + off);    off = align256(off + NSHARD * 4);
    int*    flag      = (int*)(base + off);    off = align256(off + 16);
    float*  h         = (float*)(base + off);  off = align256(off + (size_t)n * 32 * 4);
    float*  m         = (float*)(base + off);  off = align256(off + (size_t)n * 64 * 4);
    bf16_t* ysh       = (bf16_t*)(base + off); off = align256(off + (size_t)n * 32 * 2);
    float*  agg       = (float*)(base + off);  off = align256(off + (size_t)n * 64 * 4);
    float4* params    = (float4*)(base + off);

    int nb = (n + 255) / 256;
    int tb64 = (n + 63) / 64;
    int pb = (e + CHUNK - 1) / CHUNK;

    // CSR build v3: shard count -> shard scan -> partition -> distribute(row_ptr+place)
    k_detect<<<1, 64, 0, stream>>>(ei, flag);
    hipMemsetAsync(shard_cnt, 0, NSHARD * 4, stream);
    k_count<<<pb, 256, 0, stream>>>(ei, flag, shard_cnt, e, sn);
    k_scan_shard<<<1, NSHARD, 0, stream>>>(shard_cnt, shard_base, bcur);
    k_partition<<<pb, 256, 0, stream>>>(ei, flag, bcur, ebuf, e, sn);
    k_distribute<<<NSHARD, 256, 0, stream>>>(shard_base, ebuf, csr_src, row_ptr, sn, n);

    // fused embeddings
    k_embed_hm<<<tb64, 256, 0, stream>>>(x, W_in, b_in, emb1_W, emb1_b, h, m, n);

    // sheaf learner GNN layers; gnn #2 fuses params + first rotate
    int gb64 = (n * 64 + 255) / 256;
    k_gather64<<<gb64, 256, 0, stream>>>(row_ptr, csr_src, m, agg, n);
    k_gnn<<<tb64, 256, 0, stream>>>(m, agg, Ws1, Wn1, m,
                                    nullptr, nullptr, nullptr, nullptr, nullptr, nullptr, n);
    k_gather64<<<gb64, 256, 0, stream>>>(row_ptr, csr_src, m, agg, n);
    k_gnn<<<tb64, 256, 0, stream>>>(m, agg, Ws2, Wn2, m,
                                    emb2_W, emb2_b, row_ptr, h, params, ysh, n);

    // diffusion: gather -> update(+rotate) -> gather -> update(+out)
    k_gather32<<<gb64, 256, 0, stream>>>(row_ptr, csr_src, ysh, agg, n);
    k_update_mid<<<nb, 256, 0, stream>>>(h, agg, params, W_diff, ysh, n);
    k_gather32<<<gb64, 256, 0, stream>>>(row_ptr, csr_src, ysh, agg, n);
    k_update_out<<<nb, 256, 0, stream>>>(h, agg, params, W_diff + 256,
                                         W_out, b_out, (float*)d_out, n);
}